// Round 9
// baseline (412.172 us; speedup 1.0000x reference)
//
#include <hip/hip_runtime.h>
#include <hip/hip_fp16.h>

#define NPOS   4096
#define CDIM   512
#define CQK    64
#define NBATCH 4
#define L2E 1.44269504088896f

typedef _Float16 f16x8 __attribute__((ext_vector_type(8)));
typedef _Float16 f16x4 __attribute__((ext_vector_type(4)));
typedef float    f32x4 __attribute__((ext_vector_type(4)));

// LDS-only drain barrier: keeps global-load (vmcnt) prefetches in flight across
// the barrier (T4). All cross-wave traffic here is LDS, so lgkmcnt(0) suffices.
#define LDS_BARRIER() asm volatile("s_waitcnt lgkmcnt(0)\ns_barrier" ::: "memory")

// ---------------- x convert+transpose: x[b,c,n] f32 -> Xt[b,n,c] f16 ----------------
__global__ __launch_bounds__(256) void x_cvt_kernel(
    const float* __restrict__ x, _Float16* __restrict__ Xt)
{
    __shared__ _Float16 tile[64][66];
    const int b  = blockIdx.z;
    const int c0 = blockIdx.y * 64;
    const int n0 = blockIdx.x * 64;
    const int tid = threadIdx.x;

    const int rr = tid >> 4;
    const int n4 = (tid & 15) * 4;
#pragma unroll
    for (int i = 0; i < 4; ++i) {
        const int c = i * 16 + rr;
        const float4 v = *reinterpret_cast<const float4*>(
            x + (size_t)(b * CDIM + c0 + c) * NPOS + n0 + n4);
        tile[c][n4 + 0] = (_Float16)v.x;
        tile[c][n4 + 1] = (_Float16)v.y;
        tile[c][n4 + 2] = (_Float16)v.z;
        tile[c][n4 + 3] = (_Float16)v.w;
    }
    __syncthreads();

    const int col = tid & 63;
    const int r4  = tid >> 6;
#pragma unroll
    for (int i = 0; i < 16; ++i) {
        const int n = i * 4 + r4;
        Xt[((size_t)b * NPOS + n0 + n) * CDIM + c0 + col] = tile[col][n];
    }
}

// ---------------- weight convert ----------------
__global__ __launch_bounds__(256) void w_cvt_kernel(
    const float* __restrict__ wq, const float* __restrict__ bq,
    const float* __restrict__ wk, const float* __restrict__ bk,
    const float* __restrict__ wv, const float* __restrict__ bv,
    _Float16* __restrict__ Wh, float* __restrict__ biasc)
{
    const int gid = blockIdx.x * 256 + threadIdx.x;
    const int idx = gid * 4;
    const float* src;
    if (idx < 64 * 512)       src = wq + idx;
    else if (idx < 128 * 512) src = wk + (idx - 64 * 512);
    else                      src = wv + (idx - 128 * 512);
    const float4 v = *reinterpret_cast<const float4*>(src);
    f16x4 h;
    h[0] = (_Float16)v.x; h[1] = (_Float16)v.y;
    h[2] = (_Float16)v.z; h[3] = (_Float16)v.w;
    *reinterpret_cast<f16x4*>(Wh + idx) = h;
    if (gid < 640) {
        float bb;
        if (gid < 64)       bb = bq[gid];
        else if (gid < 128) bb = bk[gid - 64];
        else                bb = bv[gid - 128];
        biasc[gid] = bb;
    }
}

// ---------------- fused QKV projection GEMM (register-double-buffered) ----------------
__global__ __launch_bounds__(256) void proj_gemm_kernel(
    const _Float16* __restrict__ Wh, const float* __restrict__ biasc,
    const _Float16* __restrict__ Xt,
    _Float16* __restrict__ Qp, _Float16* __restrict__ Kp, _Float16* __restrict__ Vp)
{
    const int tid  = threadIdx.x;
    const int lane = tid & 63;
    const int w    = tid >> 6;
    const int g    = lane >> 4;
    const int lr   = lane & 15;

    const int b  = blockIdx.z;
    const int mt = blockIdx.y;
    const int m0 = mt * 64;
    const int n0 = blockIdx.x * 256 + w * 64;

    const _Float16* xb = Xt + (size_t)b * NPOS * CDIM;

    f32x4 acc[4][4];
#pragma unroll
    for (int it = 0; it < 4; ++it)
#pragma unroll
        for (int ct = 0; ct < 4; ++ct) {
            f32x4 z = {0.f, 0.f, 0.f, 0.f};
            acc[it][ct] = z;
        }

    f16x8 a0[4], b0[4], a1[4], b1[4];
    auto loadAB = [&](int kk, f16x8 (&a)[4], f16x8 (&bf)[4]) {
#pragma unroll
        for (int it = 0; it < 4; ++it)
            a[it] = *reinterpret_cast<const f16x8*>(
                Wh + (size_t)(m0 + it * 16 + lr) * CDIM + kk + 8 * g);
#pragma unroll
        for (int ct = 0; ct < 4; ++ct)
            bf[ct] = *reinterpret_cast<const f16x8*>(
                xb + (size_t)(n0 + ct * 16 + lr) * CDIM + kk + 8 * g);
    };
    auto mm16 = [&](f16x8 (&a)[4], f16x8 (&bf)[4]) {
#pragma unroll
        for (int it = 0; it < 4; ++it)
#pragma unroll
            for (int ct = 0; ct < 4; ++ct)
                acc[it][ct] = __builtin_amdgcn_mfma_f32_16x16x32_f16(a[it], bf[ct], acc[it][ct], 0, 0, 0);
    };

    loadAB(0, a0, b0);
#pragma unroll 1
    for (int p = 0; p < 8; ++p) {
        const int kk = p * 64;
        loadAB(kk + 32, a1, b1);
        mm16(a0, b0);
        if (p < 7) loadAB(kk + 64, a0, b0);
        mm16(a1, b1);
    }

    if (mt < 2) {
        _Float16* dst = (mt == 0) ? Qp : Kp;
#pragma unroll
        for (int it = 0; it < 4; ++it) {
            const int ob = it * 16 + 4 * g;
#pragma unroll
            for (int ct = 0; ct < 4; ++ct) {
                const int n = n0 + ct * 16 + lr;
                f16x4 h;
#pragma unroll
                for (int r = 0; r < 4; ++r)
                    h[r] = (_Float16)(acc[it][ct][r] + biasc[m0 + ob + r]);
                *reinterpret_cast<f16x4*>(dst + ((size_t)b * NPOS + n) * CQK + ob) = h;
            }
        }
    } else {
#pragma unroll
        for (int it = 0; it < 4; ++it)
#pragma unroll
            for (int ct = 0; ct < 4; ++ct) {
                const int n = n0 + ct * 16 + lr;
#pragma unroll
                for (int r = 0; r < 4; ++r) {
                    const int c = m0 - 128 + it * 16 + 4 * g + r;
                    Vp[((size_t)b * CDIM + c) * NPOS + n] =
                        (_Float16)(acc[it][ct][r] + biasc[m0 + it * 16 + 4 * g + r]);
                }
            }
    }
}

// ---------------- Pass 2: partial row max + sum(exp) over a j-half ----------------
// Grid (N/64, B, 2): jh = blockIdx.z selects j in [jh*2048, jh*2048+2048).
// Per-chunk MFMA chain identical to attn_out's ephase for the same j
// -> bitwise-identical E -> exp(E - max) <= 1 exactly in pass 3.
__global__ __launch_bounds__(512, 2) void attn_stats_kernel(
    const _Float16* __restrict__ Qp, const _Float16* __restrict__ Kp,
    float* __restrict__ mOut, float* __restrict__ lOut)
{
    __shared__ float lm[8 * 64];
    __shared__ float ls[8 * 64];

    const int tid  = threadIdx.x;
    const int lane = tid & 63;
    const int w    = tid >> 6;      // 0..7
    const int g    = lane >> 4;
    const int lr   = lane & 15;
    const int b    = blockIdx.y;
    const int ib   = blockIdx.x * 64;
    const int jh   = blockIdx.z;    // j-half

    f16x8 qf[4][2];
#pragma unroll
    for (int it = 0; it < 4; ++it)
#pragma unroll
        for (int ks = 0; ks < 2; ++ks)
            qf[it][ks] = *reinterpret_cast<const f16x8*>(
                Qp + (b * NPOS + ib + it * 16 + lr) * CQK + ks * 32 + 8 * g);

    const _Float16* kb = Kp + (size_t)b * NPOS * CQK + (size_t)jh * 2048 * CQK;

    float mrun[4][4], srun[4][4];
#pragma unroll
    for (int it = 0; it < 4; ++it)
#pragma unroll
        for (int r = 0; r < 4; ++r) { mrun[it][r] = -1e30f; srun[it][r] = 0.f; }

    f16x8 kA0, kA1, kB0, kB1;
    auto loadK = [&](int t, f16x8& k0, f16x8& k1) {
        const int j = t * 128 + w * 16 + lr;
        k0 = *reinterpret_cast<const f16x8*>(kb + j * CQK + 8 * g);
        k1 = *reinterpret_cast<const f16x8*>(kb + j * CQK + 32 + 8 * g);
    };
    auto step = [&](const f16x8& k0, const f16x8& k1) {
#pragma unroll
        for (int it = 0; it < 4; ++it) {
            f32x4 e = {0.f, 0.f, 0.f, 0.f};
            e = __builtin_amdgcn_mfma_f32_16x16x32_f16(qf[it][0], k0, e, 0, 0, 0);
            e = __builtin_amdgcn_mfma_f32_16x16x32_f16(qf[it][1], k1, e, 0, 0, 0);
#pragma unroll
            for (int r = 0; r < 4; ++r) {
                const float ev = e[r];
                const float mo = mrun[it][r];
                if (ev > mo) {
                    srun[it][r] = srun[it][r] * exp2f((mo - ev) * L2E) + 1.0f;
                    mrun[it][r] = ev;
                } else {
                    srun[it][r] += exp2f((ev - mo) * L2E);
                }
            }
        }
    };

    loadK(0, kA0, kA1);
#pragma unroll 1
    for (int tp = 0; tp < 8; ++tp) {
        const int t = 2 * tp;
        loadK(t + 1, kB0, kB1);
        step(kA0, kA1);
        const int tn = (t + 2 < 16) ? t + 2 : 15;
        loadK(tn, kA0, kA1);
        step(kB0, kB1);
    }

#pragma unroll
    for (int it = 0; it < 4; ++it) {
#pragma unroll
        for (int r = 0; r < 4; ++r) {
            float m = mrun[it][r], s = srun[it][r];
#pragma unroll
            for (int mask = 1; mask < 16; mask <<= 1) {
                float om = __shfl_xor(m, mask, 64);
                float os = __shfl_xor(s, mask, 64);
                float mn = fmaxf(m, om);
                s = s * exp2f((m - mn) * L2E) + os * exp2f((om - mn) * L2E);
                m = mn;
            }
            if (lr == 0) {
                const int row = it * 16 + 4 * g + r;
                lm[w * 64 + row] = m;
                ls[w * 64 + row] = s;
            }
        }
    }
    __syncthreads();

    if (tid < 64) {
        float mm = lm[tid];
#pragma unroll
        for (int w2 = 1; w2 < 8; ++w2) mm = fmaxf(mm, lm[w2 * 64 + tid]);
        float ss = 0.f;
#pragma unroll
        for (int w2 = 0; w2 < 8; ++w2) ss += ls[w2 * 64 + tid] * exp2f((lm[w2 * 64 + tid] - mm) * L2E);
        const size_t o = ((size_t)jh * NBATCH + b) * NPOS + ib + tid;
        mOut[o] = mm;
        lOut[o] = ss;
    }
}

// ---------------- Pass 3: pipelined flash PV (V double-buffered, early-issued) ----------------
// R8 structure + T14 on V: loadV(t+1) issues into the ALTERNATE register buffer at the
// top of the region (no WAR on the buffer pvphase is reading), so V's L2 latency is
// covered by a full chunk instead of just the E phase. VGPR ~128 -> ~192: per measured
// occupancy steps (waves/CU halves at 64/128/256) this keeps 8 waves/CU at grid=1 blk/CU.
// launch_bounds (512,2): measured-good codegen. A min-waves arg of 4 forces VGPR=64 and
// catastrophic spills (R4/R5 post-mortems).
__global__ __launch_bounds__(512, 2) void attn_out_kernel(
    const float* __restrict__ x, const _Float16* __restrict__ Qp, const _Float16* __restrict__ Kp,
    const _Float16* __restrict__ Vp, const float* __restrict__ mArr, const float* __restrict__ lArr,
    const float* __restrict__ gamma, float* __restrict__ out)
{
    __shared__ __align__(16) _Float16 Pl[2][64 * 128];
    char* pb0 = (char*)Pl[0];
    char* pb1 = (char*)Pl[1];

    const int tid  = threadIdx.x;
    const int lane = tid & 63;
    const int w    = tid >> 6;      // 0..7
    const int g    = lane >> 4;     // 0..3
    const int lr   = lane & 15;

    // XCD-aware decode: batch b -> XCDs {2b,2b+1} so each XCD L2 holds one batch's V+K.
    const int bid = blockIdx.x;
    const int b   = (bid & 7) >> 1;
    const int ib  = (((bid >> 3) << 1) | (bid & 1)) * 64;
    const int cw  = w * 64;

    const _Float16* kb = Kp + (size_t)b * NPOS * CQK;
    const _Float16* vb = Vp + (size_t)b * CDIM * NPOS;

    f16x8 qf[4][2];
#pragma unroll
    for (int it = 0; it < 4; ++it)
#pragma unroll
        for (int ks = 0; ks < 2; ++ks)
            qf[it][ks] = *reinterpret_cast<const f16x8*>(
                Qp + (b * NPOS + ib + it * 16 + lr) * CQK + ks * 32 + 8 * g);

    // m = max over the two j-half partial maxima
    float mreg[4][4];
#pragma unroll
    for (int it = 0; it < 4; ++it) {
        const float4 m0 = *reinterpret_cast<const float4*>(
            mArr + (size_t)b * NPOS + ib + it * 16 + 4 * g);
        const float4 m1 = *reinterpret_cast<const float4*>(
            mArr + ((size_t)NBATCH + b) * NPOS + ib + it * 16 + 4 * g);
        mreg[it][0] = fmaxf(m0.x, m1.x); mreg[it][1] = fmaxf(m0.y, m1.y);
        mreg[it][2] = fmaxf(m0.z, m1.z); mreg[it][3] = fmaxf(m0.w, m1.w);
    }

    f32x4 acc[4][4];
#pragma unroll
    for (int it = 0; it < 4; ++it)
#pragma unroll
        for (int ct = 0; ct < 4; ++ct) {
            f32x4 z = {0.f, 0.f, 0.f, 0.f};
            acc[it][ct] = z;
        }

    f16x8 vA[4][4], vB[4][4];   // double-buffered V frags (64 VGPR each)
    f16x8 kA0, kA1, kB0, kB1;   // 2-slot K prefetch

    auto loadK = [&](int t, f16x8& k0, f16x8& k1) {
        const int j = t * 128 + w * 16 + lr;
        k0 = *reinterpret_cast<const f16x8*>(kb + j * CQK + 8 * g);
        k1 = *reinterpret_cast<const f16x8*>(kb + j * CQK + 32 + 8 * g);
    };
    auto loadV = [&](int t, f16x8 (&vr)[4][4]) {
        const int jb = t * 128;
#pragma unroll
        for (int ks = 0; ks < 4; ++ks)
#pragma unroll
            for (int ct = 0; ct < 4; ++ct)
                vr[ks][ct] = *reinterpret_cast<const f16x8*>(
                    vb + (size_t)(cw + ct * 16 + lr) * NPOS + jb + ks * 32 + 8 * g);
    };
    // E phase: identical MFMA chain to attn_stats -> identical E -> exp(E-m) <= 1.
    auto ephase = [&](const f16x8& k0, const f16x8& k1, char* dst) {
#pragma unroll
        for (int it = 0; it < 4; ++it) {
            f32x4 e = {0.f, 0.f, 0.f, 0.f};
            e = __builtin_amdgcn_mfma_f32_16x16x32_f16(qf[it][0], k0, e, 0, 0, 0);
            e = __builtin_amdgcn_mfma_f32_16x16x32_f16(qf[it][1], k1, e, 0, 0, 0);
#pragma unroll
            for (int r = 0; r < 4; ++r) {
                const _Float16 p = (_Float16)exp2f((e[r] - mreg[it][r]) * L2E);
                const int i   = it * 16 + 4 * g + r;
                const int off = (i * 256 + (w * 16 + lr) * 2) ^ ((i & 15) << 4);
                *reinterpret_cast<_Float16*>(dst + off) = p;
            }
        }
    };
    auto pvphase = [&](const char* src, const f16x8 (&vr)[4][4]) {
        __builtin_amdgcn_s_setprio(1);
#pragma unroll
        for (int ks = 0; ks < 4; ++ks) {
            f16x8 pa[4];
#pragma unroll
            for (int it = 0; it < 4; ++it) {
                const int off = (it * 16 + lr) * 256 + ((ks * 64 + g * 16) ^ (lr << 4));
                pa[it] = *reinterpret_cast<const f16x8*>(src + off);
            }
#pragma unroll
            for (int it = 0; it < 4; ++it)
#pragma unroll
                for (int ct = 0; ct < 4; ++ct)
                    acc[it][ct] = __builtin_amdgcn_mfma_f32_16x16x32_f16(pa[it], vr[ks][ct], acc[it][ct], 0, 0, 0);
        }
        __builtin_amdgcn_s_setprio(0);
    };

    // Prologue: P(0) -> buf0, V(0) -> vA, K(1) prefetched.
    loadK(0, kA0, kA1);
    loadV(0, vA);
    ephase(kA0, kA1, pb0);
    loadK(1, kB0, kB1);
    __syncthreads();

#pragma unroll 1
    for (int tp = 0; tp < 15; ++tp) {
        const int t = 2 * tp;
        // chunk t (even): PV from buf0 with vA; V(t+1) issued early into vB
        loadV(t + 1, vB);
        pvphase(pb0, vA);
        ephase(kB0, kB1, pb1);          // P(t+1) -> buf1 (uses K(t+1) = kB)
        loadK(t + 2, kA0, kA1);         // K(t+2) -> kA
        LDS_BARRIER();
        // chunk t+1 (odd): PV from buf1 with vB; V(t+2) issued early into vA
        loadV(t + 2, vA);
        pvphase(pb1, vB);
        ephase(kA0, kA1, pb0);          // P(t+2) -> buf0 (uses K(t+2) = kA)
        loadK((t + 3 < 32) ? t + 3 : 31, kB0, kB1);
        LDS_BARRIER();
    }
    // tail: t = 30, 31
    loadV(31, vB);
    pvphase(pb0, vA);
    ephase(kB0, kB1, pb1);              // P(31), K(31) = kB
    LDS_BARRIER();
    pvphase(pb1, vB);

    // ---- epilogue: merge j-half (m,l), then out = gamma * acc / l + x ----
    const float gm = gamma[0];
#pragma unroll
    for (int it = 0; it < 4; ++it) {
        const int idx = ib + it * 16 + 4 * g;
        const float4 m0 = *reinterpret_cast<const float4*>(mArr + (size_t)b * NPOS + idx);
        const float4 m1 = *reinterpret_cast<const float4*>(mArr + ((size_t)NBATCH + b) * NPOS + idx);
        const float4 l0 = *reinterpret_cast<const float4*>(lArr + (size_t)b * NPOS + idx);
        const float4 l1 = *reinterpret_cast<const float4*>(lArr + ((size_t)NBATCH + b) * NPOS + idx);
        float inv[4];
        {
            const float mx = fmaxf(m0.x, m1.x);
            inv[0] = 1.0f / (l0.x * exp2f((m0.x - mx) * L2E) + l1.x * exp2f((m1.x - mx) * L2E));
            const float my = fmaxf(m0.y, m1.y);
            inv[1] = 1.0f / (l0.y * exp2f((m0.y - my) * L2E) + l1.y * exp2f((m1.y - my) * L2E));
            const float mz = fmaxf(m0.z, m1.z);
            inv[2] = 1.0f / (l0.z * exp2f((m0.z - mz) * L2E) + l1.z * exp2f((m1.z - mz) * L2E));
            const float mw = fmaxf(m0.w, m1.w);
            inv[3] = 1.0f / (l0.w * exp2f((m0.w - mw) * L2E) + l1.w * exp2f((m1.w - mw) * L2E));
        }
#pragma unroll
        for (int ct = 0; ct < 4; ++ct) {
            const int c = cw + ct * 16 + lr;
            const size_t base = (size_t)(b * CDIM + c) * NPOS + idx;
            const float4 xv = *reinterpret_cast<const float4*>(x + base);
            float4 ov;
            ov.x = gm * (acc[it][ct][0] * inv[0]) + xv.x;
            ov.y = gm * (acc[it][ct][1] * inv[1]) + xv.y;
            ov.z = gm * (acc[it][ct][2] * inv[2]) + xv.z;
            ov.w = gm * (acc[it][ct][3] * inv[3]) + xv.w;
            *reinterpret_cast<float4*>(out + base) = ov;
        }
    }
}

extern "C" void kernel_launch(void* const* d_in, const int* in_sizes, int n_in,
                              void* d_out, int out_size, void* d_ws, size_t ws_size,
                              hipStream_t stream)
{
    (void)in_sizes; (void)n_in; (void)out_size; (void)ws_size;

    const float* x     = (const float*)d_in[0];
    const float* wq    = (const float*)d_in[1];
    const float* bq    = (const float*)d_in[2];
    const float* wk    = (const float*)d_in[3];
    const float* bk    = (const float*)d_in[4];
    const float* wv    = (const float*)d_in[5];
    const float* bv    = (const float*)d_in[6];
    const float* gamma = (const float*)d_in[7];
    float* out = (float*)d_out;

    char* ws = (char*)d_ws;
    const size_t qkBytes = (size_t)NBATCH * NPOS * CQK * sizeof(_Float16);     //  2 MiB each
    const size_t vBytes  = (size_t)NBATCH * CDIM * NPOS * sizeof(_Float16);    // 16 MiB
    const size_t mlBytes = (size_t)2 * NBATCH * NPOS * sizeof(float);          // 128 KiB each (2 j-halves)
    const size_t xtBytes = (size_t)NBATCH * NPOS * CDIM * sizeof(_Float16);    // 16 MiB

    _Float16* Qp = (_Float16*)(ws);
    _Float16* Kp = (_Float16*)(ws + qkBytes);
    _Float16* Vp = (_Float16*)(ws + 2 * qkBytes);
    float* mArr  = (float*)(ws + 2 * qkBytes + vBytes);
    float* lArr  = (float*)(ws + 2 * qkBytes + vBytes + mlBytes);
    _Float16* Xt = (_Float16*)(ws + 2 * qkBytes + vBytes + 2 * mlBytes);
    _Float16* Wh = (_Float16*)(ws + 2 * qkBytes + vBytes + 2 * mlBytes + xtBytes);
    float* biasc = (float*)(ws + 2 * qkBytes + vBytes + 2 * mlBytes + xtBytes
                              + (size_t)640 * CDIM * sizeof(_Float16));
    // total ws use ~= 37.0 MiB

    w_cvt_kernel<<<dim3(640 * CDIM / 4 / 256), 256, 0, stream>>>(wq, bq, wk, bk, wv, bv, Wh, biasc);
    x_cvt_kernel<<<dim3(NPOS / 64, CDIM / 64, NBATCH), 256, 0, stream>>>(x, Xt);
    proj_gemm_kernel<<<dim3(NPOS / 256, 10, NBATCH), 256, 0, stream>>>(Wh, biasc, Xt, Qp, Kp, Vp);
    attn_stats_kernel<<<dim3(NPOS / 64, NBATCH, 2), 512, 0, stream>>>(Qp, Kp, mArr, lArr);
    attn_out_kernel<<<dim3(NPOS / 64 * NBATCH), 512, 0, stream>>>(x, Qp, Kp, Vp, mArr, lArr, gamma, out);
}

// Round 10
// 377.392 us; speedup vs baseline: 1.0922x; 1.0922x over previous
//
#include <hip/hip_runtime.h>
#include <hip/hip_fp16.h>

#define NPOS   4096
#define CDIM   512
#define CQK    64
#define NBATCH 4
#define L2E 1.44269504088896f

typedef _Float16 f16x8 __attribute__((ext_vector_type(8)));
typedef _Float16 f16x4 __attribute__((ext_vector_type(4)));
typedef float    f32x4 __attribute__((ext_vector_type(4)));

// LDS-only drain barrier: keeps global-load (vmcnt) prefetches in flight across
// the barrier (T4). All cross-wave traffic here is LDS, so lgkmcnt(0) suffices.
#define LDS_BARRIER() asm volatile("s_waitcnt lgkmcnt(0)\ns_barrier" ::: "memory")

// ---------------- x convert+transpose: x[b,c,n] f32 -> Xt[b,n,c] f16 ----------------
__global__ __launch_bounds__(256) void x_cvt_kernel(
    const float* __restrict__ x, _Float16* __restrict__ Xt)
{
    __shared__ _Float16 tile[64][66];
    const int b  = blockIdx.z;
    const int c0 = blockIdx.y * 64;
    const int n0 = blockIdx.x * 64;
    const int tid = threadIdx.x;

    const int rr = tid >> 4;
    const int n4 = (tid & 15) * 4;
#pragma unroll
    for (int i = 0; i < 4; ++i) {
        const int c = i * 16 + rr;
        const float4 v = *reinterpret_cast<const float4*>(
            x + (size_t)(b * CDIM + c0 + c) * NPOS + n0 + n4);
        tile[c][n4 + 0] = (_Float16)v.x;
        tile[c][n4 + 1] = (_Float16)v.y;
        tile[c][n4 + 2] = (_Float16)v.z;
        tile[c][n4 + 3] = (_Float16)v.w;
    }
    __syncthreads();

    const int col = tid & 63;
    const int r4  = tid >> 6;
#pragma unroll
    for (int i = 0; i < 16; ++i) {
        const int n = i * 4 + r4;
        Xt[((size_t)b * NPOS + n0 + n) * CDIM + c0 + col] = tile[col][n];
    }
}

// ---------------- weight convert ----------------
__global__ __launch_bounds__(256) void w_cvt_kernel(
    const float* __restrict__ wq, const float* __restrict__ bq,
    const float* __restrict__ wk, const float* __restrict__ bk,
    const float* __restrict__ wv, const float* __restrict__ bv,
    _Float16* __restrict__ Wh, float* __restrict__ biasc)
{
    const int gid = blockIdx.x * 256 + threadIdx.x;
    const int idx = gid * 4;
    const float* src;
    if (idx < 64 * 512)       src = wq + idx;
    else if (idx < 128 * 512) src = wk + (idx - 64 * 512);
    else                      src = wv + (idx - 128 * 512);
    const float4 v = *reinterpret_cast<const float4*>(src);
    f16x4 h;
    h[0] = (_Float16)v.x; h[1] = (_Float16)v.y;
    h[2] = (_Float16)v.z; h[3] = (_Float16)v.w;
    *reinterpret_cast<f16x4*>(Wh + idx) = h;
    if (gid < 640) {
        float bb;
        if (gid < 64)       bb = bq[gid];
        else if (gid < 128) bb = bk[gid - 64];
        else                bb = bv[gid - 128];
        biasc[gid] = bb;
    }
}

// ---------------- fused QKV projection GEMM (register-double-buffered) ----------------
__global__ __launch_bounds__(256) void proj_gemm_kernel(
    const _Float16* __restrict__ Wh, const float* __restrict__ biasc,
    const _Float16* __restrict__ Xt,
    _Float16* __restrict__ Qp, _Float16* __restrict__ Kp, _Float16* __restrict__ Vp)
{
    const int tid  = threadIdx.x;
    const int lane = tid & 63;
    const int w    = tid >> 6;
    const int g    = lane >> 4;
    const int lr   = lane & 15;

    const int b  = blockIdx.z;
    const int mt = blockIdx.y;
    const int m0 = mt * 64;
    const int n0 = blockIdx.x * 256 + w * 64;

    const _Float16* xb = Xt + (size_t)b * NPOS * CDIM;

    f32x4 acc[4][4];
#pragma unroll
    for (int it = 0; it < 4; ++it)
#pragma unroll
        for (int ct = 0; ct < 4; ++ct) {
            f32x4 z = {0.f, 0.f, 0.f, 0.f};
            acc[it][ct] = z;
        }

    f16x8 a0[4], b0[4], a1[4], b1[4];
    auto loadAB = [&](int kk, f16x8 (&a)[4], f16x8 (&bf)[4]) {
#pragma unroll
        for (int it = 0; it < 4; ++it)
            a[it] = *reinterpret_cast<const f16x8*>(
                Wh + (size_t)(m0 + it * 16 + lr) * CDIM + kk + 8 * g);
#pragma unroll
        for (int ct = 0; ct < 4; ++ct)
            bf[ct] = *reinterpret_cast<const f16x8*>(
                xb + (size_t)(n0 + ct * 16 + lr) * CDIM + kk + 8 * g);
    };
    auto mm16 = [&](f16x8 (&a)[4], f16x8 (&bf)[4]) {
#pragma unroll
        for (int it = 0; it < 4; ++it)
#pragma unroll
            for (int ct = 0; ct < 4; ++ct)
                acc[it][ct] = __builtin_amdgcn_mfma_f32_16x16x32_f16(a[it], bf[ct], acc[it][ct], 0, 0, 0);
    };

    loadAB(0, a0, b0);
#pragma unroll 1
    for (int p = 0; p < 8; ++p) {
        const int kk = p * 64;
        loadAB(kk + 32, a1, b1);
        mm16(a0, b0);
        if (p < 7) loadAB(kk + 64, a0, b0);
        mm16(a1, b1);
    }

    if (mt < 2) {
        _Float16* dst = (mt == 0) ? Qp : Kp;
#pragma unroll
        for (int it = 0; it < 4; ++it) {
            const int ob = it * 16 + 4 * g;
#pragma unroll
            for (int ct = 0; ct < 4; ++ct) {
                const int n = n0 + ct * 16 + lr;
                f16x4 h;
#pragma unroll
                for (int r = 0; r < 4; ++r)
                    h[r] = (_Float16)(acc[it][ct][r] + biasc[m0 + ob + r]);
                *reinterpret_cast<f16x4*>(dst + ((size_t)b * NPOS + n) * CQK + ob) = h;
            }
        }
    } else {
#pragma unroll
        for (int it = 0; it < 4; ++it)
#pragma unroll
            for (int ct = 0; ct < 4; ++ct) {
                const int n = n0 + ct * 16 + lr;
#pragma unroll
                for (int r = 0; r < 4; ++r) {
                    const int c = m0 - 128 + it * 16 + 4 * g + r;
                    Vp[((size_t)b * CDIM + c) * NPOS + n] =
                        (_Float16)(acc[it][ct][r] + biasc[m0 + it * 16 + 4 * g + r]);
                }
            }
    }
}

// ---------------- Pass 2: partial row max + sum(exp) over a j-half ----------------
// Grid (N/64, B, 2): jh = blockIdx.z selects j in [jh*2048, jh*2048+2048).
// Per-chunk MFMA chain identical to attn_out's ephase for the same j
// -> bitwise-identical E -> exp(E - max) <= 1 exactly in pass 3.
__global__ __launch_bounds__(512, 2) void attn_stats_kernel(
    const _Float16* __restrict__ Qp, const _Float16* __restrict__ Kp,
    float* __restrict__ mOut, float* __restrict__ lOut)
{
    __shared__ float lm[8 * 64];
    __shared__ float ls[8 * 64];

    const int tid  = threadIdx.x;
    const int lane = tid & 63;
    const int w    = tid >> 6;      // 0..7
    const int g    = lane >> 4;
    const int lr   = lane & 15;
    const int b    = blockIdx.y;
    const int ib   = blockIdx.x * 64;
    const int jh   = blockIdx.z;    // j-half

    f16x8 qf[4][2];
#pragma unroll
    for (int it = 0; it < 4; ++it)
#pragma unroll
        for (int ks = 0; ks < 2; ++ks)
            qf[it][ks] = *reinterpret_cast<const f16x8*>(
                Qp + (b * NPOS + ib + it * 16 + lr) * CQK + ks * 32 + 8 * g);

    const _Float16* kb = Kp + (size_t)b * NPOS * CQK + (size_t)jh * 2048 * CQK;

    float mrun[4][4], srun[4][4];
#pragma unroll
    for (int it = 0; it < 4; ++it)
#pragma unroll
        for (int r = 0; r < 4; ++r) { mrun[it][r] = -1e30f; srun[it][r] = 0.f; }

    f16x8 kA0, kA1, kB0, kB1;
    auto loadK = [&](int t, f16x8& k0, f16x8& k1) {
        const int j = t * 128 + w * 16 + lr;
        k0 = *reinterpret_cast<const f16x8*>(kb + j * CQK + 8 * g);
        k1 = *reinterpret_cast<const f16x8*>(kb + j * CQK + 32 + 8 * g);
    };
    auto step = [&](const f16x8& k0, const f16x8& k1) {
#pragma unroll
        for (int it = 0; it < 4; ++it) {
            f32x4 e = {0.f, 0.f, 0.f, 0.f};
            e = __builtin_amdgcn_mfma_f32_16x16x32_f16(qf[it][0], k0, e, 0, 0, 0);
            e = __builtin_amdgcn_mfma_f32_16x16x32_f16(qf[it][1], k1, e, 0, 0, 0);
#pragma unroll
            for (int r = 0; r < 4; ++r) {
                const float ev = e[r];
                const float mo = mrun[it][r];
                if (ev > mo) {
                    srun[it][r] = srun[it][r] * exp2f((mo - ev) * L2E) + 1.0f;
                    mrun[it][r] = ev;
                } else {
                    srun[it][r] += exp2f((ev - mo) * L2E);
                }
            }
        }
    };

    loadK(0, kA0, kA1);
#pragma unroll 1
    for (int tp = 0; tp < 8; ++tp) {
        const int t = 2 * tp;
        loadK(t + 1, kB0, kB1);
        step(kA0, kA1);
        const int tn = (t + 2 < 16) ? t + 2 : 15;
        loadK(tn, kA0, kA1);
        step(kB0, kB1);
    }

#pragma unroll
    for (int it = 0; it < 4; ++it) {
#pragma unroll
        for (int r = 0; r < 4; ++r) {
            float m = mrun[it][r], s = srun[it][r];
#pragma unroll
            for (int mask = 1; mask < 16; mask <<= 1) {
                float om = __shfl_xor(m, mask, 64);
                float os = __shfl_xor(s, mask, 64);
                float mn = fmaxf(m, om);
                s = s * exp2f((m - mn) * L2E) + os * exp2f((om - mn) * L2E);
                m = mn;
            }
            if (lr == 0) {
                const int row = it * 16 + 4 * g + r;
                lm[w * 64 + row] = m;
                ls[w * 64 + row] = s;
            }
        }
    }
    __syncthreads();

    if (tid < 64) {
        float mm = lm[tid];
#pragma unroll
        for (int w2 = 1; w2 < 8; ++w2) mm = fmaxf(mm, lm[w2 * 64 + tid]);
        float ss = 0.f;
#pragma unroll
        for (int w2 = 0; w2 < 8; ++w2) ss += ls[w2 * 64 + tid] * exp2f((lm[w2 * 64 + tid] - mm) * L2E);
        const size_t o = ((size_t)jh * NBATCH + b) * NPOS + ib + tid;
        mOut[o] = mm;
        lOut[o] = ss;
    }
}

// ---------------- Pass 3: pipelined flash PV (ROW-SPLIT: 32 q-rows/block) ----------------
// R8 structure with the block halved along q-rows: 32 rows x all 512 c x all j.
// Total MFMA across the grid is IDENTICAL to R8 (no E duplication, unlike the R6
// c-split); per-wave V slice (64 c) and V-load pattern unchanged. Working set drops
// to ~115 VGPR <= the allocator's measured hard 128 budget -> no spill, and grid=512
// gives 2 independent blocks/CU (4 waves/SIMD) whose barriers interleave -> the MFMA
// pipe stays fed while the other block's waves sit in E/barrier phases.
// launch_bounds (512,2): measured-good codegen. min-waves=4 forces VGPR=64+spills
// (R4/R5); V-dbuf at ~192 regs spills at the pinned 128 budget (R9).
__global__ __launch_bounds__(512, 2) void attn_out_kernel(
    const float* __restrict__ x, const _Float16* __restrict__ Qp, const _Float16* __restrict__ Kp,
    const _Float16* __restrict__ Vp, const float* __restrict__ mArr, const float* __restrict__ lArr,
    const float* __restrict__ gamma, float* __restrict__ out)
{
    __shared__ __align__(16) _Float16 Pl[2][32 * 128];   // 16 KB
    char* pb0 = (char*)Pl[0];
    char* pb1 = (char*)Pl[1];

    const int tid  = threadIdx.x;
    const int lane = tid & 63;
    const int w    = tid >> 6;      // 0..7
    const int g    = lane >> 4;     // 0..3
    const int lr   = lane & 15;

    // XCD-aware decode: batch b -> XCDs {2b,2b+1} so each XCD L2 holds one batch's V+K.
    const int bid = blockIdx.x;                    // [0, 512)
    const int b   = (bid & 7) >> 1;
    const int ib  = (((bid >> 3) << 1) | (bid & 1)) * 32;   // 32-row block
    const int cw  = w * 64;

    const _Float16* kb = Kp + (size_t)b * NPOS * CQK;
    const _Float16* vb = Vp + (size_t)b * CDIM * NPOS;

    f16x8 qf[2][2];
#pragma unroll
    for (int it = 0; it < 2; ++it)
#pragma unroll
        for (int ks = 0; ks < 2; ++ks)
            qf[it][ks] = *reinterpret_cast<const f16x8*>(
                Qp + (b * NPOS + ib + it * 16 + lr) * CQK + ks * 32 + 8 * g);

    // m = max over the two j-half partial maxima
    float mreg[2][4];
#pragma unroll
    for (int it = 0; it < 2; ++it) {
        const float4 m0 = *reinterpret_cast<const float4*>(
            mArr + (size_t)b * NPOS + ib + it * 16 + 4 * g);
        const float4 m1 = *reinterpret_cast<const float4*>(
            mArr + ((size_t)NBATCH + b) * NPOS + ib + it * 16 + 4 * g);
        mreg[it][0] = fmaxf(m0.x, m1.x); mreg[it][1] = fmaxf(m0.y, m1.y);
        mreg[it][2] = fmaxf(m0.z, m1.z); mreg[it][3] = fmaxf(m0.w, m1.w);
    }

    f32x4 acc[2][4];
#pragma unroll
    for (int it = 0; it < 2; ++it)
#pragma unroll
        for (int ct = 0; ct < 4; ++ct) {
            f32x4 z = {0.f, 0.f, 0.f, 0.f};
            acc[it][ct] = z;
        }

    f16x8 vreg[4][4];   // [ks][ct] V frags for the chunk being PV'd (unchanged from R8)
    f16x8 kA0, kA1, kB0, kB1;

    auto loadK = [&](int t, f16x8& k0, f16x8& k1) {
        const int j = t * 128 + w * 16 + lr;
        k0 = *reinterpret_cast<const f16x8*>(kb + j * CQK + 8 * g);
        k1 = *reinterpret_cast<const f16x8*>(kb + j * CQK + 32 + 8 * g);
    };
    auto loadV = [&](int t) {
        const int jb = t * 128;
#pragma unroll
        for (int ks = 0; ks < 4; ++ks)
#pragma unroll
            for (int ct = 0; ct < 4; ++ct)
                vreg[ks][ct] = *reinterpret_cast<const f16x8*>(
                    vb + (size_t)(cw + ct * 16 + lr) * NPOS + jb + ks * 32 + 8 * g);
    };
    // E phase: identical MFMA chain to attn_stats -> identical E -> exp(E-m) <= 1.
    auto ephase = [&](const f16x8& k0, const f16x8& k1, char* dst) {
#pragma unroll
        for (int it = 0; it < 2; ++it) {
            f32x4 e = {0.f, 0.f, 0.f, 0.f};
            e = __builtin_amdgcn_mfma_f32_16x16x32_f16(qf[it][0], k0, e, 0, 0, 0);
            e = __builtin_amdgcn_mfma_f32_16x16x32_f16(qf[it][1], k1, e, 0, 0, 0);
#pragma unroll
            for (int r = 0; r < 4; ++r) {
                const _Float16 p = (_Float16)exp2f((e[r] - mreg[it][r]) * L2E);
                const int i   = it * 16 + 4 * g + r;
                const int off = (i * 256 + (w * 16 + lr) * 2) ^ ((i & 15) << 4);
                *reinterpret_cast<_Float16*>(dst + off) = p;
            }
        }
    };
    auto pvphase = [&](const char* src) {
        __builtin_amdgcn_s_setprio(1);
#pragma unroll
        for (int ks = 0; ks < 4; ++ks) {
            f16x8 pa[2];
#pragma unroll
            for (int it = 0; it < 2; ++it) {
                const int off = (it * 16 + lr) * 256 + ((ks * 64 + g * 16) ^ (lr << 4));
                pa[it] = *reinterpret_cast<const f16x8*>(src + off);
            }
#pragma unroll
            for (int it = 0; it < 2; ++it)
#pragma unroll
                for (int ct = 0; ct < 4; ++ct)
                    acc[it][ct] = __builtin_amdgcn_mfma_f32_16x16x32_f16(pa[it], vreg[ks][ct], acc[it][ct], 0, 0, 0);
        }
        __builtin_amdgcn_s_setprio(0);
    };

    // Prologue: P(0) into buf0, V(0) into regs, K(1) prefetched.
    loadK(0, kA0, kA1);
    ephase(kA0, kA1, pb0);
    loadV(0);
    loadK(1, kB0, kB1);
    __syncthreads();

#pragma unroll 1
    for (int tp = 0; tp < 15; ++tp) {
        const int t = 2 * tp;
        // chunk t (even): PV from buf0
        pvphase(pb0);
        loadV(t + 1);
        ephase(kB0, kB1, pb1);          // P(t+1) -> buf1 (uses K(t+1) = kB)
        loadK(t + 2, kA0, kA1);         // K(t+2) -> kA
        LDS_BARRIER();
        // chunk t+1 (odd): PV from buf1
        pvphase(pb1);
        loadV(t + 2);
        ephase(kA0, kA1, pb0);          // P(t+2) -> buf0 (uses K(t+2) = kA)
        loadK((t + 3 < 32) ? t + 3 : 31, kB0, kB1);
        LDS_BARRIER();
    }
    // tail: t = 30, 31
    pvphase(pb0);
    loadV(31);
    ephase(kB0, kB1, pb1);              // P(31), K(31) = kB
    LDS_BARRIER();
    pvphase(pb1);

    // ---- epilogue: merge j-half (m,l), then out = gamma * acc / l + x ----
    const float gm = gamma[0];
#pragma unroll
    for (int it = 0; it < 2; ++it) {
        const int idx = ib + it * 16 + 4 * g;
        const float4 m0 = *reinterpret_cast<const float4*>(mArr + (size_t)b * NPOS + idx);
        const float4 m1 = *reinterpret_cast<const float4*>(mArr + ((size_t)NBATCH + b) * NPOS + idx);
        const float4 l0 = *reinterpret_cast<const float4*>(lArr + (size_t)b * NPOS + idx);
        const float4 l1 = *reinterpret_cast<const float4*>(lArr + ((size_t)NBATCH + b) * NPOS + idx);
        float inv[4];
        {
            const float mx = fmaxf(m0.x, m1.x);
            inv[0] = 1.0f / (l0.x * exp2f((m0.x - mx) * L2E) + l1.x * exp2f((m1.x - mx) * L2E));
            const float my = fmaxf(m0.y, m1.y);
            inv[1] = 1.0f / (l0.y * exp2f((m0.y - my) * L2E) + l1.y * exp2f((m1.y - my) * L2E));
            const float mz = fmaxf(m0.z, m1.z);
            inv[2] = 1.0f / (l0.z * exp2f((m0.z - mz) * L2E) + l1.z * exp2f((m1.z - mz) * L2E));
            const float mw = fmaxf(m0.w, m1.w);
            inv[3] = 1.0f / (l0.w * exp2f((m0.w - mw) * L2E) + l1.w * exp2f((m1.w - mw) * L2E));
        }
#pragma unroll
        for (int ct = 0; ct < 4; ++ct) {
            const int c = cw + ct * 16 + lr;
            const size_t base = (size_t)(b * CDIM + c) * NPOS + idx;
            const float4 xv = *reinterpret_cast<const float4*>(x + base);
            float4 ov;
            ov.x = gm * (acc[it][ct][0] * inv[0]) + xv.x;
            ov.y = gm * (acc[it][ct][1] * inv[1]) + xv.y;
            ov.z = gm * (acc[it][ct][2] * inv[2]) + xv.z;
            ov.w = gm * (acc[it][ct][3] * inv[3]) + xv.w;
            *reinterpret_cast<float4*>(out + base) = ov;
        }
    }
}

extern "C" void kernel_launch(void* const* d_in, const int* in_sizes, int n_in,
                              void* d_out, int out_size, void* d_ws, size_t ws_size,
                              hipStream_t stream)
{
    (void)in_sizes; (void)n_in; (void)out_size; (void)ws_size;

    const float* x     = (const float*)d_in[0];
    const float* wq    = (const float*)d_in[1];
    const float* bq    = (const float*)d_in[2];
    const float* wk    = (const float*)d_in[3];
    const float* bk    = (const float*)d_in[4];
    const float* wv    = (const float*)d_in[5];
    const float* bv    = (const float*)d_in[6];
    const float* gamma = (const float*)d_in[7];
    float* out = (float*)d_out;

    char* ws = (char*)d_ws;
    const size_t qkBytes = (size_t)NBATCH * NPOS * CQK * sizeof(_Float16);     //  2 MiB each
    const size_t vBytes  = (size_t)NBATCH * CDIM * NPOS * sizeof(_Float16);    // 16 MiB
    const size_t mlBytes = (size_t)2 * NBATCH * NPOS * sizeof(float);          // 128 KiB each (2 j-halves)
    const size_t xtBytes = (size_t)NBATCH * NPOS * CDIM * sizeof(_Float16);    // 16 MiB

    _Float16* Qp = (_Float16*)(ws);
    _Float16* Kp = (_Float16*)(ws + qkBytes);
    _Float16* Vp = (_Float16*)(ws + 2 * qkBytes);
    float* mArr  = (float*)(ws + 2 * qkBytes + vBytes);
    float* lArr  = (float*)(ws + 2 * qkBytes + vBytes + mlBytes);
    _Float16* Xt = (_Float16*)(ws + 2 * qkBytes + vBytes + 2 * mlBytes);
    _Float16* Wh = (_Float16*)(ws + 2 * qkBytes + vBytes + 2 * mlBytes + xtBytes);
    float* biasc = (float*)(ws + 2 * qkBytes + vBytes + 2 * mlBytes + xtBytes
                              + (size_t)640 * CDIM * sizeof(_Float16));
    // total ws use ~= 37.0 MiB

    w_cvt_kernel<<<dim3(640 * CDIM / 4 / 256), 256, 0, stream>>>(wq, bq, wk, bk, wv, bv, Wh, biasc);
    x_cvt_kernel<<<dim3(NPOS / 64, CDIM / 64, NBATCH), 256, 0, stream>>>(x, Xt);
    proj_gemm_kernel<<<dim3(NPOS / 256, 10, NBATCH), 256, 0, stream>>>(Wh, biasc, Xt, Qp, Kp, Vp);
    attn_stats_kernel<<<dim3(NPOS / 64, NBATCH, 2), 512, 0, stream>>>(Qp, Kp, mArr, lArr);
    attn_out_kernel<<<dim3(NPOS / 32 * NBATCH), 512, 0, stream>>>(x, Qp, Kp, Vp, mArr, lArr, gamma, out);
}

// Round 11
// 260.388 us; speedup vs baseline: 1.5829x; 1.4493x over previous
//
#include <hip/hip_runtime.h>
#include <hip/hip_fp16.h>

#define NPOS   4096
#define CDIM   512
#define CQK    64
#define NBATCH 4
#define L2E 1.44269504088896f

typedef _Float16 f16x8 __attribute__((ext_vector_type(8)));
typedef _Float16 f16x4 __attribute__((ext_vector_type(4)));
typedef float    f32x4 __attribute__((ext_vector_type(4)));

// LDS-only drain barrier: keeps global-load (vmcnt) prefetches in flight across
// the barrier (T4). All cross-wave traffic here is LDS, so lgkmcnt(0) suffices.
#define LDS_BARRIER() asm volatile("s_waitcnt lgkmcnt(0)\ns_barrier" ::: "memory")

// ---------------- x convert+transpose: x[b,c,n] f32 -> Xt[b,n,c] f16 ----------------
__global__ __launch_bounds__(256) void x_cvt_kernel(
    const float* __restrict__ x, _Float16* __restrict__ Xt)
{
    __shared__ _Float16 tile[64][66];
    const int b  = blockIdx.z;
    const int c0 = blockIdx.y * 64;
    const int n0 = blockIdx.x * 64;
    const int tid = threadIdx.x;

    const int rr = tid >> 4;
    const int n4 = (tid & 15) * 4;
#pragma unroll
    for (int i = 0; i < 4; ++i) {
        const int c = i * 16 + rr;
        const float4 v = *reinterpret_cast<const float4*>(
            x + (size_t)(b * CDIM + c0 + c) * NPOS + n0 + n4);
        tile[c][n4 + 0] = (_Float16)v.x;
        tile[c][n4 + 1] = (_Float16)v.y;
        tile[c][n4 + 2] = (_Float16)v.z;
        tile[c][n4 + 3] = (_Float16)v.w;
    }
    __syncthreads();

    const int col = tid & 63;
    const int r4  = tid >> 6;
#pragma unroll
    for (int i = 0; i < 16; ++i) {
        const int n = i * 4 + r4;
        Xt[((size_t)b * NPOS + n0 + n) * CDIM + c0 + col] = tile[col][n];
    }
}

// ---------------- weight convert ----------------
__global__ __launch_bounds__(256) void w_cvt_kernel(
    const float* __restrict__ wq, const float* __restrict__ bq,
    const float* __restrict__ wk, const float* __restrict__ bk,
    const float* __restrict__ wv, const float* __restrict__ bv,
    _Float16* __restrict__ Wh, float* __restrict__ biasc)
{
    const int gid = blockIdx.x * 256 + threadIdx.x;
    const int idx = gid * 4;
    const float* src;
    if (idx < 64 * 512)       src = wq + idx;
    else if (idx < 128 * 512) src = wk + (idx - 64 * 512);
    else                      src = wv + (idx - 128 * 512);
    const float4 v = *reinterpret_cast<const float4*>(src);
    f16x4 h;
    h[0] = (_Float16)v.x; h[1] = (_Float16)v.y;
    h[2] = (_Float16)v.z; h[3] = (_Float16)v.w;
    *reinterpret_cast<f16x4*>(Wh + idx) = h;
    if (gid < 640) {
        float bb;
        if (gid < 64)       bb = bq[gid];
        else if (gid < 128) bb = bk[gid - 64];
        else                bb = bv[gid - 128];
        biasc[gid] = bb;
    }
}

// ---------------- fused QKV projection GEMM (register-double-buffered) ----------------
__global__ __launch_bounds__(256) void proj_gemm_kernel(
    const _Float16* __restrict__ Wh, const float* __restrict__ biasc,
    const _Float16* __restrict__ Xt,
    _Float16* __restrict__ Qp, _Float16* __restrict__ Kp, _Float16* __restrict__ Vp)
{
    const int tid  = threadIdx.x;
    const int lane = tid & 63;
    const int w    = tid >> 6;
    const int g    = lane >> 4;
    const int lr   = lane & 15;

    const int b  = blockIdx.z;
    const int mt = blockIdx.y;
    const int m0 = mt * 64;
    const int n0 = blockIdx.x * 256 + w * 64;

    const _Float16* xb = Xt + (size_t)b * NPOS * CDIM;

    f32x4 acc[4][4];
#pragma unroll
    for (int it = 0; it < 4; ++it)
#pragma unroll
        for (int ct = 0; ct < 4; ++ct) {
            f32x4 z = {0.f, 0.f, 0.f, 0.f};
            acc[it][ct] = z;
        }

    f16x8 a0[4], b0[4], a1[4], b1[4];
    auto loadAB = [&](int kk, f16x8 (&a)[4], f16x8 (&bf)[4]) {
#pragma unroll
        for (int it = 0; it < 4; ++it)
            a[it] = *reinterpret_cast<const f16x8*>(
                Wh + (size_t)(m0 + it * 16 + lr) * CDIM + kk + 8 * g);
#pragma unroll
        for (int ct = 0; ct < 4; ++ct)
            bf[ct] = *reinterpret_cast<const f16x8*>(
                xb + (size_t)(n0 + ct * 16 + lr) * CDIM + kk + 8 * g);
    };
    auto mm16 = [&](f16x8 (&a)[4], f16x8 (&bf)[4]) {
#pragma unroll
        for (int it = 0; it < 4; ++it)
#pragma unroll
            for (int ct = 0; ct < 4; ++ct)
                acc[it][ct] = __builtin_amdgcn_mfma_f32_16x16x32_f16(a[it], bf[ct], acc[it][ct], 0, 0, 0);
    };

    loadAB(0, a0, b0);
#pragma unroll 1
    for (int p = 0; p < 8; ++p) {
        const int kk = p * 64;
        loadAB(kk + 32, a1, b1);
        mm16(a0, b0);
        if (p < 7) loadAB(kk + 64, a0, b0);
        mm16(a1, b1);
    }

    if (mt < 2) {
        _Float16* dst = (mt == 0) ? Qp : Kp;
#pragma unroll
        for (int it = 0; it < 4; ++it) {
            const int ob = it * 16 + 4 * g;
#pragma unroll
            for (int ct = 0; ct < 4; ++ct) {
                const int n = n0 + ct * 16 + lr;
                f16x4 h;
#pragma unroll
                for (int r = 0; r < 4; ++r)
                    h[r] = (_Float16)(acc[it][ct][r] + biasc[m0 + ob + r]);
                *reinterpret_cast<f16x4*>(dst + ((size_t)b * NPOS + n) * CQK + ob) = h;
            }
        }
    } else {
#pragma unroll
        for (int it = 0; it < 4; ++it)
#pragma unroll
            for (int ct = 0; ct < 4; ++ct) {
                const int n = n0 + ct * 16 + lr;
#pragma unroll
                for (int r = 0; r < 4; ++r) {
                    const int c = m0 - 128 + it * 16 + 4 * g + r;
                    Vp[((size_t)b * CDIM + c) * NPOS + n] =
                        (_Float16)(acc[it][ct][r] + biasc[m0 + it * 16 + 4 * g + r]);
                }
            }
    }
}

// ---------------- Pass 2: partial row max + sum(exp) over a j-half ----------------
// Grid (N/64, B, 2): jh = blockIdx.z selects j in [jh*2048, jh*2048+2048).
// Per-chunk MFMA chain identical to attn_out's ephase for the same j
// -> bitwise-identical E -> exp(E - max) <= 1 exactly in pass 3.
__global__ __launch_bounds__(512, 2) void attn_stats_kernel(
    const _Float16* __restrict__ Qp, const _Float16* __restrict__ Kp,
    float* __restrict__ mOut, float* __restrict__ lOut)
{
    __shared__ float lm[8 * 64];
    __shared__ float ls[8 * 64];

    const int tid  = threadIdx.x;
    const int lane = tid & 63;
    const int w    = tid >> 6;      // 0..7
    const int g    = lane >> 4;
    const int lr   = lane & 15;
    const int b    = blockIdx.y;
    const int ib   = blockIdx.x * 64;
    const int jh   = blockIdx.z;    // j-half

    f16x8 qf[4][2];
#pragma unroll
    for (int it = 0; it < 4; ++it)
#pragma unroll
        for (int ks = 0; ks < 2; ++ks)
            qf[it][ks] = *reinterpret_cast<const f16x8*>(
                Qp + (b * NPOS + ib + it * 16 + lr) * CQK + ks * 32 + 8 * g);

    const _Float16* kb = Kp + (size_t)b * NPOS * CQK + (size_t)jh * 2048 * CQK;

    float mrun[4][4], srun[4][4];
#pragma unroll
    for (int it = 0; it < 4; ++it)
#pragma unroll
        for (int r = 0; r < 4; ++r) { mrun[it][r] = -1e30f; srun[it][r] = 0.f; }

    f16x8 kA0, kA1, kB0, kB1;
    auto loadK = [&](int t, f16x8& k0, f16x8& k1) {
        const int j = t * 128 + w * 16 + lr;
        k0 = *reinterpret_cast<const f16x8*>(kb + j * CQK + 8 * g);
        k1 = *reinterpret_cast<const f16x8*>(kb + j * CQK + 32 + 8 * g);
    };
    auto step = [&](const f16x8& k0, const f16x8& k1) {
#pragma unroll
        for (int it = 0; it < 4; ++it) {
            f32x4 e = {0.f, 0.f, 0.f, 0.f};
            e = __builtin_amdgcn_mfma_f32_16x16x32_f16(qf[it][0], k0, e, 0, 0, 0);
            e = __builtin_amdgcn_mfma_f32_16x16x32_f16(qf[it][1], k1, e, 0, 0, 0);
#pragma unroll
            for (int r = 0; r < 4; ++r) {
                const float ev = e[r];
                const float mo = mrun[it][r];
                if (ev > mo) {
                    srun[it][r] = srun[it][r] * exp2f((mo - ev) * L2E) + 1.0f;
                    mrun[it][r] = ev;
                } else {
                    srun[it][r] += exp2f((ev - mo) * L2E);
                }
            }
        }
    };

    loadK(0, kA0, kA1);
#pragma unroll 1
    for (int tp = 0; tp < 8; ++tp) {
        const int t = 2 * tp;
        loadK(t + 1, kB0, kB1);
        step(kA0, kA1);
        const int tn = (t + 2 < 16) ? t + 2 : 15;
        loadK(tn, kA0, kA1);
        step(kB0, kB1);
    }

#pragma unroll
    for (int it = 0; it < 4; ++it) {
#pragma unroll
        for (int r = 0; r < 4; ++r) {
            float m = mrun[it][r], s = srun[it][r];
#pragma unroll
            for (int mask = 1; mask < 16; mask <<= 1) {
                float om = __shfl_xor(m, mask, 64);
                float os = __shfl_xor(s, mask, 64);
                float mn = fmaxf(m, om);
                s = s * exp2f((m - mn) * L2E) + os * exp2f((om - mn) * L2E);
                m = mn;
            }
            if (lr == 0) {
                const int row = it * 16 + 4 * g + r;
                lm[w * 64 + row] = m;
                ls[w * 64 + row] = s;
            }
        }
    }
    __syncthreads();

    if (tid < 64) {
        float mm = lm[tid];
#pragma unroll
        for (int w2 = 1; w2 < 8; ++w2) mm = fmaxf(mm, lm[w2 * 64 + tid]);
        float ss = 0.f;
#pragma unroll
        for (int w2 = 0; w2 < 8; ++w2) ss += ls[w2 * 64 + tid] * exp2f((lm[w2 * 64 + tid] - mm) * L2E);
        const size_t o = ((size_t)jh * NBATCH + b) * NPOS + ib + tid;
        mOut[o] = mm;
        lOut[o] = ss;
    }
}

// ---------------- Pass 3: pipelined flash PV — 4 P-buffers, 1 barrier / 2 chunks ----------------
// R8 structure (best measured: 64 q-rows x 512 c, 8 waves, 128-j chunks, VGPR=128) with the
// double-buffer deepened to 4 LDS P buffers: region R PVs chunks {t,t+1} from {br0,br1}
// (written before the preceding barrier) while writing P(t+2)->bw0, P(t+3)->bw1. Reads and
// writes touch disjoint buffers, so ONE barrier per region (2 chunks) suffices: 32 -> 16
// barrier-drain events. K keeps the 2-slot rotation (each slot consumed then reloaded 4
// chunks ahead); V single-buffered with the same cover as R8. Zero extra registers.
// launch_bounds (512,2): measured-good codegen. min-waves=4 forces VGPR=64+spills (R4/R5);
// anything past ~128 VGPR working set spills (R9).
__global__ __launch_bounds__(512, 2) void attn_out_kernel(
    const float* __restrict__ x, const _Float16* __restrict__ Qp, const _Float16* __restrict__ Kp,
    const _Float16* __restrict__ Vp, const float* __restrict__ mArr, const float* __restrict__ lArr,
    const float* __restrict__ gamma, float* __restrict__ out)
{
    __shared__ __align__(16) _Float16 Pl[4][64 * 128];   // 64 KB
    char* pbA = (char*)Pl[0];
    char* pbB = (char*)Pl[1];
    char* pbC = (char*)Pl[2];
    char* pbD = (char*)Pl[3];

    const int tid  = threadIdx.x;
    const int lane = tid & 63;
    const int w    = tid >> 6;      // 0..7
    const int g    = lane >> 4;     // 0..3
    const int lr   = lane & 15;

    // XCD-aware decode: batch b -> XCDs {2b,2b+1} so each XCD L2 holds one batch's V+K.
    const int bid = blockIdx.x;
    const int b   = (bid & 7) >> 1;
    const int ib  = (((bid >> 3) << 1) | (bid & 1)) * 64;
    const int cw  = w * 64;

    const _Float16* kb = Kp + (size_t)b * NPOS * CQK;
    const _Float16* vb = Vp + (size_t)b * CDIM * NPOS;

    f16x8 qf[4][2];
#pragma unroll
    for (int it = 0; it < 4; ++it)
#pragma unroll
        for (int ks = 0; ks < 2; ++ks)
            qf[it][ks] = *reinterpret_cast<const f16x8*>(
                Qp + (b * NPOS + ib + it * 16 + lr) * CQK + ks * 32 + 8 * g);

    // m = max over the two j-half partial maxima
    float mreg[4][4];
#pragma unroll
    for (int it = 0; it < 4; ++it) {
        const float4 m0 = *reinterpret_cast<const float4*>(
            mArr + (size_t)b * NPOS + ib + it * 16 + 4 * g);
        const float4 m1 = *reinterpret_cast<const float4*>(
            mArr + ((size_t)NBATCH + b) * NPOS + ib + it * 16 + 4 * g);
        mreg[it][0] = fmaxf(m0.x, m1.x); mreg[it][1] = fmaxf(m0.y, m1.y);
        mreg[it][2] = fmaxf(m0.z, m1.z); mreg[it][3] = fmaxf(m0.w, m1.w);
    }

    f32x4 acc[4][4];
#pragma unroll
    for (int it = 0; it < 4; ++it)
#pragma unroll
        for (int ct = 0; ct < 4; ++ct) {
            f32x4 z = {0.f, 0.f, 0.f, 0.f};
            acc[it][ct] = z;
        }

    f16x8 vreg[4][4];   // [ks][ct] V frags for the chunk being PV'd
    f16x8 kA0, kA1, kB0, kB1;

    auto loadK = [&](int t, f16x8& k0, f16x8& k1) {
        const int tc = (t < 32) ? t : 31;
        const int j = tc * 128 + w * 16 + lr;
        k0 = *reinterpret_cast<const f16x8*>(kb + j * CQK + 8 * g);
        k1 = *reinterpret_cast<const f16x8*>(kb + j * CQK + 32 + 8 * g);
    };
    auto loadV = [&](int t) {
        const int tc = (t < 32) ? t : 31;
        const int jb = tc * 128;
#pragma unroll
        for (int ks = 0; ks < 4; ++ks)
#pragma unroll
            for (int ct = 0; ct < 4; ++ct)
                vreg[ks][ct] = *reinterpret_cast<const f16x8*>(
                    vb + (size_t)(cw + ct * 16 + lr) * NPOS + jb + ks * 32 + 8 * g);
    };
    // E phase: identical MFMA chain to attn_stats -> identical E -> exp(E-m) <= 1.
    auto ephase = [&](const f16x8& k0, const f16x8& k1, char* dst) {
#pragma unroll
        for (int it = 0; it < 4; ++it) {
            f32x4 e = {0.f, 0.f, 0.f, 0.f};
            e = __builtin_amdgcn_mfma_f32_16x16x32_f16(qf[it][0], k0, e, 0, 0, 0);
            e = __builtin_amdgcn_mfma_f32_16x16x32_f16(qf[it][1], k1, e, 0, 0, 0);
#pragma unroll
            for (int r = 0; r < 4; ++r) {
                const _Float16 p = (_Float16)exp2f((e[r] - mreg[it][r]) * L2E);
                const int i   = it * 16 + 4 * g + r;
                const int off = (i * 256 + (w * 16 + lr) * 2) ^ ((i & 15) << 4);
                *reinterpret_cast<_Float16*>(dst + off) = p;
            }
        }
    };
    auto pvphase = [&](const char* src) {
        __builtin_amdgcn_s_setprio(1);
#pragma unroll
        for (int ks = 0; ks < 4; ++ks) {
            f16x8 pa[4];
#pragma unroll
            for (int it = 0; it < 4; ++it) {
                const int off = (it * 16 + lr) * 256 + ((ks * 64 + g * 16) ^ (lr << 4));
                pa[it] = *reinterpret_cast<const f16x8*>(src + off);
            }
#pragma unroll
            for (int it = 0; it < 4; ++it)
#pragma unroll
                for (int ct = 0; ct < 4; ++ct)
                    acc[it][ct] = __builtin_amdgcn_mfma_f32_16x16x32_f16(pa[it], vreg[ks][ct], acc[it][ct], 0, 0, 0);
        }
        __builtin_amdgcn_s_setprio(0);
    };

    // One region = 2 chunks {t, t+1}: PV from (r0, r1), E writes P(t+2)->w0, P(t+3)->w1.
    // K slots enter holding K(t+2) (kA) and K(t+3) (kB) and are reloaded 4 ahead.
    auto region = [&](int t, char* r0, char* r1, char* w0, char* w1) {
        pvphase(r0);                // chunk t (V(t) in vreg)
        loadV(t + 1);
        ephase(kA0, kA1, w0);       // P(t+2) using K(t+2)
        loadK(t + 4, kA0, kA1);     // K(t+4)
        pvphase(r1);                // chunk t+1 (waits V(t+1); covered by ephase+loadK)
        loadV(t + 2);
        ephase(kB0, kB1, w1);       // P(t+3) using K(t+3)
        loadK(t + 5, kB0, kB1);     // K(t+5)
        LDS_BARRIER();
    };

    // Prologue: P(0)->A, P(1)->B, V(0), K(2)/K(3) in the slots.
    loadK(0, kA0, kA1);
    loadV(0);
    loadK(1, kB0, kB1);
    ephase(kA0, kA1, pbA);          // P(0)
    ephase(kB0, kB1, pbB);          // P(1)
    loadK(2, kA0, kA1);
    loadK(3, kB0, kB1);
    __syncthreads();

#pragma unroll 1
    for (int tp = 0; tp < 8; ++tp) {
        region(4 * tp,     pbA, pbB, pbC, pbD);   // chunks 4tp, 4tp+1
        region(4 * tp + 2, pbC, pbD, pbA, pbB);   // chunks 4tp+2, 4tp+3
    }
    // (final region's E/K work is clamped-harmless; all 32 chunks PV'd)

    // ---- epilogue: merge j-half (m,l), then out = gamma * acc / l + x ----
    const float gm = gamma[0];
#pragma unroll
    for (int it = 0; it < 4; ++it) {
        const int idx = ib + it * 16 + 4 * g;
        const float4 m0 = *reinterpret_cast<const float4*>(mArr + (size_t)b * NPOS + idx);
        const float4 m1 = *reinterpret_cast<const float4*>(mArr + ((size_t)NBATCH + b) * NPOS + idx);
        const float4 l0 = *reinterpret_cast<const float4*>(lArr + (size_t)b * NPOS + idx);
        const float4 l1 = *reinterpret_cast<const float4*>(lArr + ((size_t)NBATCH + b) * NPOS + idx);
        float inv[4];
        {
            const float mx = fmaxf(m0.x, m1.x);
            inv[0] = 1.0f / (l0.x * exp2f((m0.x - mx) * L2E) + l1.x * exp2f((m1.x - mx) * L2E));
            const float my = fmaxf(m0.y, m1.y);
            inv[1] = 1.0f / (l0.y * exp2f((m0.y - my) * L2E) + l1.y * exp2f((m1.y - my) * L2E));
            const float mz = fmaxf(m0.z, m1.z);
            inv[2] = 1.0f / (l0.z * exp2f((m0.z - mz) * L2E) + l1.z * exp2f((m1.z - mz) * L2E));
            const float mw = fmaxf(m0.w, m1.w);
            inv[3] = 1.0f / (l0.w * exp2f((m0.w - mw) * L2E) + l1.w * exp2f((m1.w - mw) * L2E));
        }
#pragma unroll
        for (int ct = 0; ct < 4; ++ct) {
            const int c = cw + ct * 16 + lr;
            const size_t base = (size_t)(b * CDIM + c) * NPOS + idx;
            const float4 xv = *reinterpret_cast<const float4*>(x + base);
            float4 ov;
            ov.x = gm * (acc[it][ct][0] * inv[0]) + xv.x;
            ov.y = gm * (acc[it][ct][1] * inv[1]) + xv.y;
            ov.z = gm * (acc[it][ct][2] * inv[2]) + xv.z;
            ov.w = gm * (acc[it][ct][3] * inv[3]) + xv.w;
            *reinterpret_cast<float4*>(out + base) = ov;
        }
    }
}

extern "C" void kernel_launch(void* const* d_in, const int* in_sizes, int n_in,
                              void* d_out, int out_size, void* d_ws, size_t ws_size,
                              hipStream_t stream)
{
    (void)in_sizes; (void)n_in; (void)out_size; (void)ws_size;

    const float* x     = (const float*)d_in[0];
    const float* wq    = (const float*)d_in[1];
    const float* bq    = (const float*)d_in[2];
    const float* wk    = (const float*)d_in[3];
    const float* bk    = (const float*)d_in[4];
    const float* wv    = (const float*)d_in[5];
    const float* bv    = (const float*)d_in[6];
    const float* gamma = (const float*)d_in[7];
    float* out = (float*)d_out;

    char* ws = (char*)d_ws;
    const size_t qkBytes = (size_t)NBATCH * NPOS * CQK * sizeof(_Float16);     //  2 MiB each
    const size_t vBytes  = (size_t)NBATCH * CDIM * NPOS * sizeof(_Float16);    // 16 MiB
    const size_t mlBytes = (size_t)2 * NBATCH * NPOS * sizeof(float);          // 128 KiB each (2 j-halves)
    const size_t xtBytes = (size_t)NBATCH * NPOS * CDIM * sizeof(_Float16);    // 16 MiB

    _Float16* Qp = (_Float16*)(ws);
    _Float16* Kp = (_Float16*)(ws + qkBytes);
    _Float16* Vp = (_Float16*)(ws + 2 * qkBytes);
    float* mArr  = (float*)(ws + 2 * qkBytes + vBytes);
    float* lArr  = (float*)(ws + 2 * qkBytes + vBytes + mlBytes);
    _Float16* Xt = (_Float16*)(ws + 2 * qkBytes + vBytes + 2 * mlBytes);
    _Float16* Wh = (_Float16*)(ws + 2 * qkBytes + vBytes + 2 * mlBytes + xtBytes);
    float* biasc = (float*)(ws + 2 * qkBytes + vBytes + 2 * mlBytes + xtBytes
                              + (size_t)640 * CDIM * sizeof(_Float16));
    // total ws use ~= 37.0 MiB

    w_cvt_kernel<<<dim3(640 * CDIM / 4 / 256), 256, 0, stream>>>(wq, bq, wk, bk, wv, bv, Wh, biasc);
    x_cvt_kernel<<<dim3(NPOS / 64, CDIM / 64, NBATCH), 256, 0, stream>>>(x, Xt);
    proj_gemm_kernel<<<dim3(NPOS / 256, 10, NBATCH), 256, 0, stream>>>(Wh, biasc, Xt, Qp, Kp, Vp);
    attn_stats_kernel<<<dim3(NPOS / 64, NBATCH, 2), 512, 0, stream>>>(Qp, Kp, mArr, lArr);
    attn_out_kernel<<<dim3(NPOS / 64 * NBATCH), 512, 0, stream>>>(x, Qp, Kp, Vp, mArr, lArr, gamma, out);
}

// Round 12
// 258.883 us; speedup vs baseline: 1.5921x; 1.0058x over previous
//
#include <hip/hip_runtime.h>
#include <hip/hip_fp16.h>

#define NPOS   4096
#define CDIM   512
#define CQK    64
#define NBATCH 4
#define L2E 1.44269504088896f

typedef _Float16 f16x8 __attribute__((ext_vector_type(8)));
typedef _Float16 f16x4 __attribute__((ext_vector_type(4)));
typedef float    f32x4 __attribute__((ext_vector_type(4)));

// LDS-only drain barrier: keeps global-load (vmcnt) prefetches in flight across
// the barrier (T4). All cross-wave traffic here is LDS, so lgkmcnt(0) suffices.
#define LDS_BARRIER() asm volatile("s_waitcnt lgkmcnt(0)\ns_barrier" ::: "memory")

// ---------------- x convert+transpose: x[b,c,n] f32 -> Xt[b,n,c] f16 ----------------
__global__ __launch_bounds__(256) void x_cvt_kernel(
    const float* __restrict__ x, _Float16* __restrict__ Xt)
{
    __shared__ _Float16 tile[64][66];
    const int b  = blockIdx.z;
    const int c0 = blockIdx.y * 64;
    const int n0 = blockIdx.x * 64;
    const int tid = threadIdx.x;

    const int rr = tid >> 4;
    const int n4 = (tid & 15) * 4;
#pragma unroll
    for (int i = 0; i < 4; ++i) {
        const int c = i * 16 + rr;
        const float4 v = *reinterpret_cast<const float4*>(
            x + (size_t)(b * CDIM + c0 + c) * NPOS + n0 + n4);
        tile[c][n4 + 0] = (_Float16)v.x;
        tile[c][n4 + 1] = (_Float16)v.y;
        tile[c][n4 + 2] = (_Float16)v.z;
        tile[c][n4 + 3] = (_Float16)v.w;
    }
    __syncthreads();

    const int col = tid & 63;
    const int r4  = tid >> 6;
#pragma unroll
    for (int i = 0; i < 16; ++i) {
        const int n = i * 4 + r4;
        Xt[((size_t)b * NPOS + n0 + n) * CDIM + c0 + col] = tile[col][n];
    }
}

// ---------------- weight convert ----------------
__global__ __launch_bounds__(256) void w_cvt_kernel(
    const float* __restrict__ wq, const float* __restrict__ bq,
    const float* __restrict__ wk, const float* __restrict__ bk,
    const float* __restrict__ wv, const float* __restrict__ bv,
    _Float16* __restrict__ Wh, float* __restrict__ biasc)
{
    const int gid = blockIdx.x * 256 + threadIdx.x;
    const int idx = gid * 4;
    const float* src;
    if (idx < 64 * 512)       src = wq + idx;
    else if (idx < 128 * 512) src = wk + (idx - 64 * 512);
    else                      src = wv + (idx - 128 * 512);
    const float4 v = *reinterpret_cast<const float4*>(src);
    f16x4 h;
    h[0] = (_Float16)v.x; h[1] = (_Float16)v.y;
    h[2] = (_Float16)v.z; h[3] = (_Float16)v.w;
    *reinterpret_cast<f16x4*>(Wh + idx) = h;
    if (gid < 640) {
        float bb;
        if (gid < 64)       bb = bq[gid];
        else if (gid < 128) bb = bk[gid - 64];
        else                bb = bv[gid - 128];
        biasc[gid] = bb;
    }
}

// ---------------- fused QKV projection GEMM (register-double-buffered) ----------------
__global__ __launch_bounds__(256) void proj_gemm_kernel(
    const _Float16* __restrict__ Wh, const float* __restrict__ biasc,
    const _Float16* __restrict__ Xt,
    _Float16* __restrict__ Qp, _Float16* __restrict__ Kp, _Float16* __restrict__ Vp)
{
    const int tid  = threadIdx.x;
    const int lane = tid & 63;
    const int w    = tid >> 6;
    const int g    = lane >> 4;
    const int lr   = lane & 15;

    const int b  = blockIdx.z;
    const int mt = blockIdx.y;
    const int m0 = mt * 64;
    const int n0 = blockIdx.x * 256 + w * 64;

    const _Float16* xb = Xt + (size_t)b * NPOS * CDIM;

    f32x4 acc[4][4];
#pragma unroll
    for (int it = 0; it < 4; ++it)
#pragma unroll
        for (int ct = 0; ct < 4; ++ct) {
            f32x4 z = {0.f, 0.f, 0.f, 0.f};
            acc[it][ct] = z;
        }

    f16x8 a0[4], b0[4], a1[4], b1[4];
    auto loadAB = [&](int kk, f16x8 (&a)[4], f16x8 (&bf)[4]) {
#pragma unroll
        for (int it = 0; it < 4; ++it)
            a[it] = *reinterpret_cast<const f16x8*>(
                Wh + (size_t)(m0 + it * 16 + lr) * CDIM + kk + 8 * g);
#pragma unroll
        for (int ct = 0; ct < 4; ++ct)
            bf[ct] = *reinterpret_cast<const f16x8*>(
                xb + (size_t)(n0 + ct * 16 + lr) * CDIM + kk + 8 * g);
    };
    auto mm16 = [&](f16x8 (&a)[4], f16x8 (&bf)[4]) {
#pragma unroll
        for (int it = 0; it < 4; ++it)
#pragma unroll
            for (int ct = 0; ct < 4; ++ct)
                acc[it][ct] = __builtin_amdgcn_mfma_f32_16x16x32_f16(a[it], bf[ct], acc[it][ct], 0, 0, 0);
    };

    loadAB(0, a0, b0);
#pragma unroll 1
    for (int p = 0; p < 8; ++p) {
        const int kk = p * 64;
        loadAB(kk + 32, a1, b1);
        mm16(a0, b0);
        if (p < 7) loadAB(kk + 64, a0, b0);
        mm16(a1, b1);
    }

    if (mt < 2) {
        _Float16* dst = (mt == 0) ? Qp : Kp;
#pragma unroll
        for (int it = 0; it < 4; ++it) {
            const int ob = it * 16 + 4 * g;
#pragma unroll
            for (int ct = 0; ct < 4; ++ct) {
                const int n = n0 + ct * 16 + lr;
                f16x4 h;
#pragma unroll
                for (int r = 0; r < 4; ++r)
                    h[r] = (_Float16)(acc[it][ct][r] + biasc[m0 + ob + r]);
                *reinterpret_cast<f16x4*>(dst + ((size_t)b * NPOS + n) * CQK + ob) = h;
            }
        }
    } else {
#pragma unroll
        for (int it = 0; it < 4; ++it)
#pragma unroll
            for (int ct = 0; ct < 4; ++ct) {
                const int n = n0 + ct * 16 + lr;
#pragma unroll
                for (int r = 0; r < 4; ++r) {
                    const int c = m0 - 128 + it * 16 + 4 * g + r;
                    Vp[((size_t)b * CDIM + c) * NPOS + n] =
                        (_Float16)(acc[it][ct][r] + biasc[m0 + it * 16 + 4 * g + r]);
                }
            }
    }
}

// ---------------- Pass 2: partial row max + sum(exp) over a j-half ----------------
// Grid (N/64, B, 2): jh = blockIdx.z selects j in [jh*2048, jh*2048+2048).
// Per-chunk MFMA chain identical to attn_out's ephase for the same j
// -> bitwise-identical E -> exp(E - max) <= 1 exactly in pass 3.
__global__ __launch_bounds__(512, 2) void attn_stats_kernel(
    const _Float16* __restrict__ Qp, const _Float16* __restrict__ Kp,
    float* __restrict__ mOut, float* __restrict__ lOut)
{
    __shared__ float lm[8 * 64];
    __shared__ float ls[8 * 64];

    const int tid  = threadIdx.x;
    const int lane = tid & 63;
    const int w    = tid >> 6;      // 0..7
    const int g    = lane >> 4;
    const int lr   = lane & 15;
    const int b    = blockIdx.y;
    const int ib   = blockIdx.x * 64;
    const int jh   = blockIdx.z;    // j-half

    f16x8 qf[4][2];
#pragma unroll
    for (int it = 0; it < 4; ++it)
#pragma unroll
        for (int ks = 0; ks < 2; ++ks)
            qf[it][ks] = *reinterpret_cast<const f16x8*>(
                Qp + (b * NPOS + ib + it * 16 + lr) * CQK + ks * 32 + 8 * g);

    const _Float16* kb = Kp + (size_t)b * NPOS * CQK + (size_t)jh * 2048 * CQK;

    float mrun[4][4], srun[4][4];
#pragma unroll
    for (int it = 0; it < 4; ++it)
#pragma unroll
        for (int r = 0; r < 4; ++r) { mrun[it][r] = -1e30f; srun[it][r] = 0.f; }

    f16x8 kA0, kA1, kB0, kB1;
    auto loadK = [&](int t, f16x8& k0, f16x8& k1) {
        const int j = t * 128 + w * 16 + lr;
        k0 = *reinterpret_cast<const f16x8*>(kb + j * CQK + 8 * g);
        k1 = *reinterpret_cast<const f16x8*>(kb + j * CQK + 32 + 8 * g);
    };
    auto step = [&](const f16x8& k0, const f16x8& k1) {
#pragma unroll
        for (int it = 0; it < 4; ++it) {
            f32x4 e = {0.f, 0.f, 0.f, 0.f};
            e = __builtin_amdgcn_mfma_f32_16x16x32_f16(qf[it][0], k0, e, 0, 0, 0);
            e = __builtin_amdgcn_mfma_f32_16x16x32_f16(qf[it][1], k1, e, 0, 0, 0);
#pragma unroll
            for (int r = 0; r < 4; ++r) {
                const float ev = e[r];
                const float mo = mrun[it][r];
                if (ev > mo) {
                    srun[it][r] = srun[it][r] * exp2f((mo - ev) * L2E) + 1.0f;
                    mrun[it][r] = ev;
                } else {
                    srun[it][r] += exp2f((ev - mo) * L2E);
                }
            }
        }
    };

    loadK(0, kA0, kA1);
#pragma unroll 1
    for (int tp = 0; tp < 8; ++tp) {
        const int t = 2 * tp;
        loadK(t + 1, kB0, kB1);
        step(kA0, kA1);
        const int tn = (t + 2 < 16) ? t + 2 : 15;
        loadK(tn, kA0, kA1);
        step(kB0, kB1);
    }

#pragma unroll
    for (int it = 0; it < 4; ++it) {
#pragma unroll
        for (int r = 0; r < 4; ++r) {
            float m = mrun[it][r], s = srun[it][r];
#pragma unroll
            for (int mask = 1; mask < 16; mask <<= 1) {
                float om = __shfl_xor(m, mask, 64);
                float os = __shfl_xor(s, mask, 64);
                float mn = fmaxf(m, om);
                s = s * exp2f((m - mn) * L2E) + os * exp2f((om - mn) * L2E);
                m = mn;
            }
            if (lr == 0) {
                const int row = it * 16 + 4 * g + r;
                lm[w * 64 + row] = m;
                ls[w * 64 + row] = s;
            }
        }
    }
    __syncthreads();

    if (tid < 64) {
        float mm = lm[tid];
#pragma unroll
        for (int w2 = 1; w2 < 8; ++w2) mm = fmaxf(mm, lm[w2 * 64 + tid]);
        float ss = 0.f;
#pragma unroll
        for (int w2 = 0; w2 < 8; ++w2) ss += ls[w2 * 64 + tid] * exp2f((lm[w2 * 64 + tid] - mm) * L2E);
        const size_t o = ((size_t)jh * NBATCH + b) * NPOS + ib + tid;
        mOut[o] = mm;
        lOut[o] = ss;
    }
}

// ---------------- Pass 3: pipelined flash PV — E-first region, half-split V pipeline ----------------
// R8 structure (64 q-rows x 512 c, 8 waves, 128-j chunks, 2 P-buffers, 1 barrier/chunk,
// VGPR=128) with the region reordered E-FIRST and V split into two 32-VGPR half-buffers
// (same 64 VGPR total as R8's vreg[4][4]):
//   ephase(K(t+1)) ; loadK(t+2) ; pvhalf(P(t),vA) ; loadVh(t+1->vA) ;
//   pvhalf(P(t),vB) ; loadVh(t+1->vB) ; barrier
// V(t+1) halves are consumed a half-chunk + E-phase + barrier after issue (~3x R8's
// cover for the V L2 round-trip), and the E MFMA burst overlaps V flight. Zero extra
// registers, zero extra work, same barrier count.
// launch_bounds (512,2): measured-good codegen. min-waves=4 forces VGPR=64+spills
// (R4/R5); a 2nd full vreg buffer (+64 VGPR) spills at the pinned 128 budget (R9).
__global__ __launch_bounds__(512, 2) void attn_out_kernel(
    const float* __restrict__ x, const _Float16* __restrict__ Qp, const _Float16* __restrict__ Kp,
    const _Float16* __restrict__ Vp, const float* __restrict__ mArr, const float* __restrict__ lArr,
    const float* __restrict__ gamma, float* __restrict__ out)
{
    __shared__ __align__(16) _Float16 Pl[2][64 * 128];
    char* pb0 = (char*)Pl[0];
    char* pb1 = (char*)Pl[1];

    const int tid  = threadIdx.x;
    const int lane = tid & 63;
    const int w    = tid >> 6;      // 0..7
    const int g    = lane >> 4;     // 0..3
    const int lr   = lane & 15;

    // XCD-aware decode: batch b -> XCDs {2b,2b+1} so each XCD L2 holds one batch's V+K.
    const int bid = blockIdx.x;
    const int b   = (bid & 7) >> 1;
    const int ib  = (((bid >> 3) << 1) | (bid & 1)) * 64;
    const int cw  = w * 64;

    const _Float16* kb = Kp + (size_t)b * NPOS * CQK;
    const _Float16* vb = Vp + (size_t)b * CDIM * NPOS;

    f16x8 qf[4][2];
#pragma unroll
    for (int it = 0; it < 4; ++it)
#pragma unroll
        for (int ks = 0; ks < 2; ++ks)
            qf[it][ks] = *reinterpret_cast<const f16x8*>(
                Qp + (b * NPOS + ib + it * 16 + lr) * CQK + ks * 32 + 8 * g);

    // m = max over the two j-half partial maxima
    float mreg[4][4];
#pragma unroll
    for (int it = 0; it < 4; ++it) {
        const float4 m0 = *reinterpret_cast<const float4*>(
            mArr + (size_t)b * NPOS + ib + it * 16 + 4 * g);
        const float4 m1 = *reinterpret_cast<const float4*>(
            mArr + ((size_t)NBATCH + b) * NPOS + ib + it * 16 + 4 * g);
        mreg[it][0] = fmaxf(m0.x, m1.x); mreg[it][1] = fmaxf(m0.y, m1.y);
        mreg[it][2] = fmaxf(m0.z, m1.z); mreg[it][3] = fmaxf(m0.w, m1.w);
    }

    f32x4 acc[4][4];
#pragma unroll
    for (int it = 0; it < 4; ++it)
#pragma unroll
        for (int ct = 0; ct < 4; ++ct) {
            f32x4 z = {0.f, 0.f, 0.f, 0.f};
            acc[it][ct] = z;
        }

    f16x8 vA[2][4], vB[2][4];   // half-chunk V buffers (ks 0-1 / ks 2-3), 32 VGPR each
    f16x8 kA0, kA1, kB0, kB1;   // 2-slot K prefetch

    auto loadK = [&](int t, f16x8& k0, f16x8& k1) {
        const int tc = (t < 32) ? t : 31;
        const int j = tc * 128 + w * 16 + lr;
        k0 = *reinterpret_cast<const f16x8*>(kb + j * CQK + 8 * g);
        k1 = *reinterpret_cast<const f16x8*>(kb + j * CQK + 32 + 8 * g);
    };
    auto loadVh = [&](int t, int h, f16x8 (&vr)[2][4]) {
        const int tc = (t < 32) ? t : 31;
        const int jb = tc * 128;
#pragma unroll
        for (int ks2 = 0; ks2 < 2; ++ks2)
#pragma unroll
            for (int ct = 0; ct < 4; ++ct)
                vr[ks2][ct] = *reinterpret_cast<const f16x8*>(
                    vb + (size_t)(cw + ct * 16 + lr) * NPOS + jb + (2 * h + ks2) * 32 + 8 * g);
    };
    // E phase: identical MFMA chain to attn_stats -> identical E -> exp(E-m) <= 1.
    auto ephase = [&](const f16x8& k0, const f16x8& k1, char* dst) {
#pragma unroll
        for (int it = 0; it < 4; ++it) {
            f32x4 e = {0.f, 0.f, 0.f, 0.f};
            e = __builtin_amdgcn_mfma_f32_16x16x32_f16(qf[it][0], k0, e, 0, 0, 0);
            e = __builtin_amdgcn_mfma_f32_16x16x32_f16(qf[it][1], k1, e, 0, 0, 0);
#pragma unroll
            for (int r = 0; r < 4; ++r) {
                const _Float16 p = (_Float16)exp2f((e[r] - mreg[it][r]) * L2E);
                const int i   = it * 16 + 4 * g + r;
                const int off = (i * 256 + (w * 16 + lr) * 2) ^ ((i & 15) << 4);
                *reinterpret_cast<_Float16*>(dst + off) = p;
            }
        }
    };
    auto pvhalf = [&](const char* src, int h, const f16x8 (&vr)[2][4]) {
        __builtin_amdgcn_s_setprio(1);
#pragma unroll
        for (int ks2 = 0; ks2 < 2; ++ks2) {
            const int ks = 2 * h + ks2;
            f16x8 pa[4];
#pragma unroll
            for (int it = 0; it < 4; ++it) {
                const int off = (it * 16 + lr) * 256 + ((ks * 64 + g * 16) ^ (lr << 4));
                pa[it] = *reinterpret_cast<const f16x8*>(src + off);
            }
#pragma unroll
            for (int it = 0; it < 4; ++it)
#pragma unroll
                for (int ct = 0; ct < 4; ++ct)
                    acc[it][ct] = __builtin_amdgcn_mfma_f32_16x16x32_f16(pa[it], vr[ks2][ct], acc[it][ct], 0, 0, 0);
        }
        __builtin_amdgcn_s_setprio(0);
    };

    // One region = chunk t: E(t+1) first (overlaps V(t+1) flight), then PV(t) in halves
    // with V(t+1) halves issued immediately after their vreg half is consumed.
    auto region = [&](int t, char* rbuf, char* wbuf, f16x8& ku0, f16x8& ku1,
                      f16x8& kl0, f16x8& kl1) {
        ephase(ku0, ku1, wbuf);         // P(t+1) using K(t+1)
        loadK(t + 2, kl0, kl1);         // K(t+2) into the other slot
        pvhalf(rbuf, 0, vA);            // PV(t) ks 0-1
        loadVh(t + 1, 0, vA);           // V(t+1) ks 0-1
        pvhalf(rbuf, 1, vB);            // PV(t) ks 2-3
        loadVh(t + 1, 1, vB);           // V(t+1) ks 2-3
        LDS_BARRIER();
    };

    // Prologue: P(0) -> pb0, V(0) -> vA/vB, K(1) -> kA.
    loadK(0, kA0, kA1);
    loadVh(0, 0, vA);
    loadVh(0, 1, vB);
    ephase(kA0, kA1, pb0);              // P(0) (uses K(0) in kA)
    loadK(1, kA0, kA1);                 // K(1) -> kA (K(0) dead)
    __syncthreads();

#pragma unroll 1
    for (int tp = 0; tp < 16; ++tp) {
        const int t = 2 * tp;
        region(t,     pb0, pb1, kA0, kA1, kB0, kB1);   // chunk t:   P in pb0, K(t+1)=kA
        region(t + 1, pb1, pb0, kB0, kB1, kA0, kA1);   // chunk t+1: P in pb1, K(t+2)=kB
    }
    // (final region's ephase/loadK/loadV are tail-clamped and harmless; all 32 chunks PV'd)

    // ---- epilogue: merge j-half (m,l), then out = gamma * acc / l + x ----
    const float gm = gamma[0];
#pragma unroll
    for (int it = 0; it < 4; ++it) {
        const int idx = ib + it * 16 + 4 * g;
        const float4 m0 = *reinterpret_cast<const float4*>(mArr + (size_t)b * NPOS + idx);
        const float4 m1 = *reinterpret_cast<const float4*>(mArr + ((size_t)NBATCH + b) * NPOS + idx);
        const float4 l0 = *reinterpret_cast<const float4*>(lArr + (size_t)b * NPOS + idx);
        const float4 l1 = *reinterpret_cast<const float4*>(lArr + ((size_t)NBATCH + b) * NPOS + idx);
        float inv[4];
        {
            const float mx = fmaxf(m0.x, m1.x);
            inv[0] = 1.0f / (l0.x * exp2f((m0.x - mx) * L2E) + l1.x * exp2f((m1.x - mx) * L2E));
            const float my = fmaxf(m0.y, m1.y);
            inv[1] = 1.0f / (l0.y * exp2f((m0.y - my) * L2E) + l1.y * exp2f((m1.y - my) * L2E));
            const float mz = fmaxf(m0.z, m1.z);
            inv[2] = 1.0f / (l0.z * exp2f((m0.z - mz) * L2E) + l1.z * exp2f((m1.z - mz) * L2E));
            const float mw = fmaxf(m0.w, m1.w);
            inv[3] = 1.0f / (l0.w * exp2f((m0.w - mw) * L2E) + l1.w * exp2f((m1.w - mw) * L2E));
        }
#pragma unroll
        for (int ct = 0; ct < 4; ++ct) {
            const int c = cw + ct * 16 + lr;
            const size_t base = (size_t)(b * CDIM + c) * NPOS + idx;
            const float4 xv = *reinterpret_cast<const float4*>(x + base);
            float4 ov;
            ov.x = gm * (acc[it][ct][0] * inv[0]) + xv.x;
            ov.y = gm * (acc[it][ct][1] * inv[1]) + xv.y;
            ov.z = gm * (acc[it][ct][2] * inv[2]) + xv.z;
            ov.w = gm * (acc[it][ct][3] * inv[3]) + xv.w;
            *reinterpret_cast<float4*>(out + base) = ov;
        }
    }
}

extern "C" void kernel_launch(void* const* d_in, const int* in_sizes, int n_in,
                              void* d_out, int out_size, void* d_ws, size_t ws_size,
                              hipStream_t stream)
{
    (void)in_sizes; (void)n_in; (void)out_size; (void)ws_size;

    const float* x     = (const float*)d_in[0];
    const float* wq    = (const float*)d_in[1];
    const float* bq    = (const float*)d_in[2];
    const float* wk    = (const float*)d_in[3];
    const float* bk    = (const float*)d_in[4];
    const float* wv    = (const float*)d_in[5];
    const float* bv    = (const float*)d_in[6];
    const float* gamma = (const float*)d_in[7];
    float* out = (float*)d_out;

    char* ws = (char*)d_ws;
    const size_t qkBytes = (size_t)NBATCH * NPOS * CQK * sizeof(_Float16);     //  2 MiB each
    const size_t vBytes  = (size_t)NBATCH * CDIM * NPOS * sizeof(_Float16);    // 16 MiB
    const size_t mlBytes = (size_t)2 * NBATCH * NPOS * sizeof(float);          // 128 KiB each (2 j-halves)
    const size_t xtBytes = (size_t)NBATCH * NPOS * CDIM * sizeof(_Float16);    // 16 MiB

    _Float16* Qp = (_Float16*)(ws);
    _Float16* Kp = (_Float16*)(ws + qkBytes);
    _Float16* Vp = (_Float16*)(ws + 2 * qkBytes);
    float* mArr  = (float*)(ws + 2 * qkBytes + vBytes);
    float* lArr  = (float*)(ws + 2 * qkBytes + vBytes + mlBytes);
    _Float16* Xt = (_Float16*)(ws + 2 * qkBytes + vBytes + 2 * mlBytes);
    _Float16* Wh = (_Float16*)(ws + 2 * qkBytes + vBytes + 2 * mlBytes + xtBytes);
    float* biasc = (float*)(ws + 2 * qkBytes + vBytes + 2 * mlBytes + xtBytes
                              + (size_t)640 * CDIM * sizeof(_Float16));
    // total ws use ~= 37.0 MiB

    w_cvt_kernel<<<dim3(640 * CDIM / 4 / 256), 256, 0, stream>>>(wq, bq, wk, bk, wv, bv, Wh, biasc);
    x_cvt_kernel<<<dim3(NPOS / 64, CDIM / 64, NBATCH), 256, 0, stream>>>(x, Xt);
    proj_gemm_kernel<<<dim3(NPOS / 256, 10, NBATCH), 256, 0, stream>>>(Wh, biasc, Xt, Qp, Kp, Vp);
    attn_stats_kernel<<<dim3(NPOS / 64, NBATCH, 2), 512, 0, stream>>>(Qp, Kp, mArr, lArr);
    attn_out_kernel<<<dim3(NPOS / 64 * NBATCH), 512, 0, stream>>>(x, Qp, Kp, Vp, mArr, lArr, gamma, out);
}

// Round 13
// 232.136 us; speedup vs baseline: 1.7756x; 1.1152x over previous
//
#include <hip/hip_runtime.h>
#include <hip/hip_fp16.h>

#define NPOS   4096
#define CDIM   512
#define CQK    64
#define NBATCH 4
#define L2E 1.44269504088896f

typedef _Float16 f16x8 __attribute__((ext_vector_type(8)));
typedef _Float16 f16x4 __attribute__((ext_vector_type(4)));
typedef float    f32x4 __attribute__((ext_vector_type(4)));

// LDS-only drain barrier: keeps global-load (vmcnt) prefetches in flight across
// the barrier (T4). All cross-wave traffic here is LDS, so lgkmcnt(0) suffices.
#define LDS_BARRIER() asm volatile("s_waitcnt lgkmcnt(0)\ns_barrier" ::: "memory")

// ---------------- x convert+transpose: x[b,c,n] f32 -> Xt[b,n,c] f16 ----------------
__global__ __launch_bounds__(256) void x_cvt_kernel(
    const float* __restrict__ x, _Float16* __restrict__ Xt)
{
    __shared__ _Float16 tile[64][66];
    const int b  = blockIdx.z;
    const int c0 = blockIdx.y * 64;
    const int n0 = blockIdx.x * 64;
    const int tid = threadIdx.x;

    const int rr = tid >> 4;
    const int n4 = (tid & 15) * 4;
#pragma unroll
    for (int i = 0; i < 4; ++i) {
        const int c = i * 16 + rr;
        const float4 v = *reinterpret_cast<const float4*>(
            x + (size_t)(b * CDIM + c0 + c) * NPOS + n0 + n4);
        tile[c][n4 + 0] = (_Float16)v.x;
        tile[c][n4 + 1] = (_Float16)v.y;
        tile[c][n4 + 2] = (_Float16)v.z;
        tile[c][n4 + 3] = (_Float16)v.w;
    }
    __syncthreads();

    const int col = tid & 63;
    const int r4  = tid >> 6;
#pragma unroll
    for (int i = 0; i < 16; ++i) {
        const int n = i * 4 + r4;
        Xt[((size_t)b * NPOS + n0 + n) * CDIM + c0 + col] = tile[col][n];
    }
}

// ---------------- weight convert ----------------
__global__ __launch_bounds__(256) void w_cvt_kernel(
    const float* __restrict__ wq, const float* __restrict__ bq,
    const float* __restrict__ wk, const float* __restrict__ bk,
    const float* __restrict__ wv, const float* __restrict__ bv,
    _Float16* __restrict__ Wh, float* __restrict__ biasc)
{
    const int gid = blockIdx.x * 256 + threadIdx.x;
    const int idx = gid * 4;
    const float* src;
    if (idx < 64 * 512)       src = wq + idx;
    else if (idx < 128 * 512) src = wk + (idx - 64 * 512);
    else                      src = wv + (idx - 128 * 512);
    const float4 v = *reinterpret_cast<const float4*>(src);
    f16x4 h;
    h[0] = (_Float16)v.x; h[1] = (_Float16)v.y;
    h[2] = (_Float16)v.z; h[3] = (_Float16)v.w;
    *reinterpret_cast<f16x4*>(Wh + idx) = h;
    if (gid < 640) {
        float bb;
        if (gid < 64)       bb = bq[gid];
        else if (gid < 128) bb = bk[gid - 64];
        else                bb = bv[gid - 128];
        biasc[gid] = bb;
    }
}

// ---------------- fused QKV projection GEMM: 128x128 tile, LDS double-buffered ----------------
// 256 threads / 4 waves (2 m-halves x 2 n-halves), BK=32, K=512 -> 16 steps.
// T14 split staging: global->reg issued before compute, ds_write after, 1 barrier/step.
// LDS rows are 32 f16 (64 B) linear: frag b128 reads distribute 8 lanes per 16B
// bank-group (the wave64-b128 floor) -> no pad needed, 16B alignment everywhere.
// Accumulation order over K identical to the previous kernel -> bitwise-same Q/K/V.
// Tile m0=0 holds Q rows (wave m-half 0) and K rows (m-half 1); m0>=128 is V.
__global__ __launch_bounds__(256) void proj_gemm_kernel(
    const _Float16* __restrict__ Wh, const float* __restrict__ biasc,
    const _Float16* __restrict__ Xt,
    _Float16* __restrict__ Qp, _Float16* __restrict__ Kp, _Float16* __restrict__ Vp)
{
    __shared__ __align__(16) _Float16 As[2][128 * 32];
    __shared__ __align__(16) _Float16 Bs[2][128 * 32];

    const int tid  = threadIdx.x;
    const int lane = tid & 63;
    const int w    = tid >> 6;       // 0..3
    const int wr   = w >> 1;         // m-half
    const int wc   = w & 1;          // n-half
    const int g    = lane >> 4;
    const int lr   = lane & 15;

    const int b  = blockIdx.z;
    const int m0 = blockIdx.y * 128;
    const int n0 = blockIdx.x * 128;

    const _Float16* xb = Xt + (size_t)b * NPOS * CDIM;

    // staging map: thread t -> row = t>>2 (+64/round), 16B chunk = t&3
    const int srow = tid >> 2;
    const int schk = (tid & 3) * 8;

    f16x8 sA[2], sB[2];
    auto gload = [&](int kk) {
#pragma unroll
        for (int rnd = 0; rnd < 2; ++rnd) {
            const int row = srow + rnd * 64;
            sA[rnd] = *reinterpret_cast<const f16x8*>(
                Wh + (size_t)(m0 + row) * CDIM + kk + schk);
            sB[rnd] = *reinterpret_cast<const f16x8*>(
                xb + (size_t)(n0 + row) * CDIM + kk + schk);
        }
    };
    auto dswrite = [&](int buf) {
#pragma unroll
        for (int rnd = 0; rnd < 2; ++rnd) {
            const int row = srow + rnd * 64;
            *reinterpret_cast<f16x8*>(&As[buf][row * 32 + schk]) = sA[rnd];
            *reinterpret_cast<f16x8*>(&Bs[buf][row * 32 + schk]) = sB[rnd];
        }
    };

    f32x4 acc[4][4];
#pragma unroll
    for (int it = 0; it < 4; ++it)
#pragma unroll
        for (int ct = 0; ct < 4; ++ct) {
            f32x4 z = {0.f, 0.f, 0.f, 0.f};
            acc[it][ct] = z;
        }

    auto compute = [&](int buf) {
        f16x8 a[4], bf[4];
#pragma unroll
        for (int it = 0; it < 4; ++it)
            a[it] = *reinterpret_cast<const f16x8*>(
                &As[buf][(wr * 64 + it * 16 + lr) * 32 + 8 * g]);
#pragma unroll
        for (int ct = 0; ct < 4; ++ct)
            bf[ct] = *reinterpret_cast<const f16x8*>(
                &Bs[buf][(wc * 64 + ct * 16 + lr) * 32 + 8 * g]);
#pragma unroll
        for (int it = 0; it < 4; ++it)
#pragma unroll
            for (int ct = 0; ct < 4; ++ct)
                acc[it][ct] = __builtin_amdgcn_mfma_f32_16x16x32_f16(a[it], bf[ct], acc[it][ct], 0, 0, 0);
    };

    // Prologue
    gload(0);
    dswrite(0);
    __syncthreads();

#pragma unroll 1
    for (int t = 0; t < 16; ++t) {
        if (t < 15) gload((t + 1) * 32);      // issue early (T14): latency under compute
        compute(t & 1);
        if (t < 15) dswrite((t + 1) & 1);     // write the OTHER buffer (no hazard w/ reads)
        __syncthreads();
    }

    // ---- epilogue ----
    if (m0 == 0) {
        // wr==0 -> Q rows 0..63 ; wr==1 -> K rows 64..127
        _Float16* dst = (wr == 0) ? Qp : Kp;
#pragma unroll
        for (int it = 0; it < 4; ++it) {
            const int gmb = m0 + wr * 64 + it * 16 + 4 * g;   // global W row base
            const int ob  = gmb & 63;                          // o within Q/K
#pragma unroll
            for (int ct = 0; ct < 4; ++ct) {
                const int n = n0 + wc * 64 + ct * 16 + lr;
                f16x4 h;
#pragma unroll
                for (int r = 0; r < 4; ++r)
                    h[r] = (_Float16)(acc[it][ct][r] + biasc[gmb + r]);
                *reinterpret_cast<f16x4*>(dst + ((size_t)b * NPOS + n) * CQK + ob) = h;
            }
        }
    } else {
#pragma unroll
        for (int it = 0; it < 4; ++it) {
            const int gmb = m0 + wr * 64 + it * 16 + 4 * g;
#pragma unroll
            for (int ct = 0; ct < 4; ++ct) {
                const int n = n0 + wc * 64 + ct * 16 + lr;
#pragma unroll
                for (int r = 0; r < 4; ++r) {
                    const int c = gmb + r - 128;
                    Vp[((size_t)b * CDIM + c) * NPOS + n] =
                        (_Float16)(acc[it][ct][r] + biasc[gmb + r]);
                }
            }
        }
    }
}

// ---------------- Pass 2: partial row max + sum(exp) over a j-half ----------------
// Grid (N/64, B, 2): jh = blockIdx.z selects j in [jh*2048, jh*2048+2048).
// Per-chunk MFMA chain identical to attn_out's ephase for the same j
// -> bitwise-identical E -> exp(E - max) <= 1 exactly in pass 3.
__global__ __launch_bounds__(512, 2) void attn_stats_kernel(
    const _Float16* __restrict__ Qp, const _Float16* __restrict__ Kp,
    float* __restrict__ mOut, float* __restrict__ lOut)
{
    __shared__ float lm[8 * 64];
    __shared__ float ls[8 * 64];

    const int tid  = threadIdx.x;
    const int lane = tid & 63;
    const int w    = tid >> 6;      // 0..7
    const int g    = lane >> 4;
    const int lr   = lane & 15;
    const int b    = blockIdx.y;
    const int ib   = blockIdx.x * 64;
    const int jh   = blockIdx.z;    // j-half

    f16x8 qf[4][2];
#pragma unroll
    for (int it = 0; it < 4; ++it)
#pragma unroll
        for (int ks = 0; ks < 2; ++ks)
            qf[it][ks] = *reinterpret_cast<const f16x8*>(
                Qp + (b * NPOS + ib + it * 16 + lr) * CQK + ks * 32 + 8 * g);

    const _Float16* kb = Kp + (size_t)b * NPOS * CQK + (size_t)jh * 2048 * CQK;

    float mrun[4][4], srun[4][4];
#pragma unroll
    for (int it = 0; it < 4; ++it)
#pragma unroll
        for (int r = 0; r < 4; ++r) { mrun[it][r] = -1e30f; srun[it][r] = 0.f; }

    f16x8 kA0, kA1, kB0, kB1;
    auto loadK = [&](int t, f16x8& k0, f16x8& k1) {
        const int j = t * 128 + w * 16 + lr;
        k0 = *reinterpret_cast<const f16x8*>(kb + j * CQK + 8 * g);
        k1 = *reinterpret_cast<const f16x8*>(kb + j * CQK + 32 + 8 * g);
    };
    auto step = [&](const f16x8& k0, const f16x8& k1) {
#pragma unroll
        for (int it = 0; it < 4; ++it) {
            f32x4 e = {0.f, 0.f, 0.f, 0.f};
            e = __builtin_amdgcn_mfma_f32_16x16x32_f16(qf[it][0], k0, e, 0, 0, 0);
            e = __builtin_amdgcn_mfma_f32_16x16x32_f16(qf[it][1], k1, e, 0, 0, 0);
#pragma unroll
            for (int r = 0; r < 4; ++r) {
                const float ev = e[r];
                const float mo = mrun[it][r];
                if (ev > mo) {
                    srun[it][r] = srun[it][r] * exp2f((mo - ev) * L2E) + 1.0f;
                    mrun[it][r] = ev;
                } else {
                    srun[it][r] += exp2f((ev - mo) * L2E);
                }
            }
        }
    };

    loadK(0, kA0, kA1);
#pragma unroll 1
    for (int tp = 0; tp < 8; ++tp) {
        const int t = 2 * tp;
        loadK(t + 1, kB0, kB1);
        step(kA0, kA1);
        const int tn = (t + 2 < 16) ? t + 2 : 15;
        loadK(tn, kA0, kA1);
        step(kB0, kB1);
    }

#pragma unroll
    for (int it = 0; it < 4; ++it) {
#pragma unroll
        for (int r = 0; r < 4; ++r) {
            float m = mrun[it][r], s = srun[it][r];
#pragma unroll
            for (int mask = 1; mask < 16; mask <<= 1) {
                float om = __shfl_xor(m, mask, 64);
                float os = __shfl_xor(s, mask, 64);
                float mn = fmaxf(m, om);
                s = s * exp2f((m - mn) * L2E) + os * exp2f((om - mn) * L2E);
                m = mn;
            }
            if (lr == 0) {
                const int row = it * 16 + 4 * g + r;
                lm[w * 64 + row] = m;
                ls[w * 64 + row] = s;
            }
        }
    }
    __syncthreads();

    if (tid < 64) {
        float mm = lm[tid];
#pragma unroll
        for (int w2 = 1; w2 < 8; ++w2) mm = fmaxf(mm, lm[w2 * 64 + tid]);
        float ss = 0.f;
#pragma unroll
        for (int w2 = 0; w2 < 8; ++w2) ss += ls[w2 * 64 + tid] * exp2f((lm[w2 * 64 + tid] - mm) * L2E);
        const size_t o = ((size_t)jh * NBATCH + b) * NPOS + ib + tid;
        mOut[o] = mm;
        lOut[o] = ss;
    }
}

// ---------------- Pass 3: pipelined flash PV — E-first region, half-split V pipeline ----------------
// (R12 structure, best measured class: 64 q-rows x 512 c, 8 waves, 128-j chunks,
// 2 P-buffers, 1 barrier/chunk, VGPR=128. Frozen this round.)
__global__ __launch_bounds__(512, 2) void attn_out_kernel(
    const float* __restrict__ x, const _Float16* __restrict__ Qp, const _Float16* __restrict__ Kp,
    const _Float16* __restrict__ Vp, const float* __restrict__ mArr, const float* __restrict__ lArr,
    const float* __restrict__ gamma, float* __restrict__ out)
{
    __shared__ __align__(16) _Float16 Pl[2][64 * 128];
    char* pb0 = (char*)Pl[0];
    char* pb1 = (char*)Pl[1];

    const int tid  = threadIdx.x;
    const int lane = tid & 63;
    const int w    = tid >> 6;      // 0..7
    const int g    = lane >> 4;     // 0..3
    const int lr   = lane & 15;

    // XCD-aware decode: batch b -> XCDs {2b,2b+1} so each XCD L2 holds one batch's V+K.
    const int bid = blockIdx.x;
    const int b   = (bid & 7) >> 1;
    const int ib  = (((bid >> 3) << 1) | (bid & 1)) * 64;
    const int cw  = w * 64;

    const _Float16* kb = Kp + (size_t)b * NPOS * CQK;
    const _Float16* vb = Vp + (size_t)b * CDIM * NPOS;

    f16x8 qf[4][2];
#pragma unroll
    for (int it = 0; it < 4; ++it)
#pragma unroll
        for (int ks = 0; ks < 2; ++ks)
            qf[it][ks] = *reinterpret_cast<const f16x8*>(
                Qp + (b * NPOS + ib + it * 16 + lr) * CQK + ks * 32 + 8 * g);

    // m = max over the two j-half partial maxima
    float mreg[4][4];
#pragma unroll
    for (int it = 0; it < 4; ++it) {
        const float4 m0 = *reinterpret_cast<const float4*>(
            mArr + (size_t)b * NPOS + ib + it * 16 + 4 * g);
        const float4 m1 = *reinterpret_cast<const float4*>(
            mArr + ((size_t)NBATCH + b) * NPOS + ib + it * 16 + 4 * g);
        mreg[it][0] = fmaxf(m0.x, m1.x); mreg[it][1] = fmaxf(m0.y, m1.y);
        mreg[it][2] = fmaxf(m0.z, m1.z); mreg[it][3] = fmaxf(m0.w, m1.w);
    }

    f32x4 acc[4][4];
#pragma unroll
    for (int it = 0; it < 4; ++it)
#pragma unroll
        for (int ct = 0; ct < 4; ++ct) {
            f32x4 z = {0.f, 0.f, 0.f, 0.f};
            acc[it][ct] = z;
        }

    f16x8 vA[2][4], vB[2][4];   // half-chunk V buffers (ks 0-1 / ks 2-3), 32 VGPR each
    f16x8 kA0, kA1, kB0, kB1;   // 2-slot K prefetch

    auto loadK = [&](int t, f16x8& k0, f16x8& k1) {
        const int tc = (t < 32) ? t : 31;
        const int j = tc * 128 + w * 16 + lr;
        k0 = *reinterpret_cast<const f16x8*>(kb + j * CQK + 8 * g);
        k1 = *reinterpret_cast<const f16x8*>(kb + j * CQK + 32 + 8 * g);
    };
    auto loadVh = [&](int t, int h, f16x8 (&vr)[2][4]) {
        const int tc = (t < 32) ? t : 31;
        const int jb = tc * 128;
#pragma unroll
        for (int ks2 = 0; ks2 < 2; ++ks2)
#pragma unroll
            for (int ct = 0; ct < 4; ++ct)
                vr[ks2][ct] = *reinterpret_cast<const f16x8*>(
                    vb + (size_t)(cw + ct * 16 + lr) * NPOS + jb + (2 * h + ks2) * 32 + 8 * g);
    };
    // E phase: identical MFMA chain to attn_stats -> identical E -> exp(E-m) <= 1.
    auto ephase = [&](const f16x8& k0, const f16x8& k1, char* dst) {
#pragma unroll
        for (int it = 0; it < 4; ++it) {
            f32x4 e = {0.f, 0.f, 0.f, 0.f};
            e = __builtin_amdgcn_mfma_f32_16x16x32_f16(qf[it][0], k0, e, 0, 0, 0);
            e = __builtin_amdgcn_mfma_f32_16x16x32_f16(qf[it][1], k1, e, 0, 0, 0);
#pragma unroll
            for (int r = 0; r < 4; ++r) {
                const _Float16 p = (_Float16)exp2f((e[r] - mreg[it][r]) * L2E);
                const int i   = it * 16 + 4 * g + r;
                const int off = (i * 256 + (w * 16 + lr) * 2) ^ ((i & 15) << 4);
                *reinterpret_cast<_Float16*>(dst + off) = p;
            }
        }
    };
    auto pvhalf = [&](const char* src, int h, const f16x8 (&vr)[2][4]) {
        __builtin_amdgcn_s_setprio(1);
#pragma unroll
        for (int ks2 = 0; ks2 < 2; ++ks2) {
            const int ks = 2 * h + ks2;
            f16x8 pa[4];
#pragma unroll
            for (int it = 0; it < 4; ++it) {
                const int off = (it * 16 + lr) * 256 + ((ks * 64 + g * 16) ^ (lr << 4));
                pa[it] = *reinterpret_cast<const f16x8*>(src + off);
            }
#pragma unroll
            for (int it = 0; it < 4; ++it)
#pragma unroll
                for (int ct = 0; ct < 4; ++ct)
                    acc[it][ct] = __builtin_amdgcn_mfma_f32_16x16x32_f16(pa[it], vr[ks2][ct], acc[it][ct], 0, 0, 0);
        }
        __builtin_amdgcn_s_setprio(0);
    };

    // One region = chunk t: E(t+1) first (overlaps V(t+1) flight), then PV(t) in halves
    // with V(t+1) halves issued immediately after their vreg half is consumed.
    auto region = [&](int t, char* rbuf, char* wbuf, f16x8& ku0, f16x8& ku1,
                      f16x8& kl0, f16x8& kl1) {
        ephase(ku0, ku1, wbuf);         // P(t+1) using K(t+1)
        loadK(t + 2, kl0, kl1);         // K(t+2) into the other slot
        pvhalf(rbuf, 0, vA);            // PV(t) ks 0-1
        loadVh(t + 1, 0, vA);           // V(t+1) ks 0-1
        pvhalf(rbuf, 1, vB);            // PV(t) ks 2-3
        loadVh(t + 1, 1, vB);           // V(t+1) ks 2-3
        LDS_BARRIER();
    };

    // Prologue: P(0) -> pb0, V(0) -> vA/vB, K(1) -> kA.
    loadK(0, kA0, kA1);
    loadVh(0, 0, vA);
    loadVh(0, 1, vB);
    ephase(kA0, kA1, pb0);              // P(0) (uses K(0) in kA)
    loadK(1, kA0, kA1);                 // K(1) -> kA (K(0) dead)
    __syncthreads();

#pragma unroll 1
    for (int tp = 0; tp < 16; ++tp) {
        const int t = 2 * tp;
        region(t,     pb0, pb1, kA0, kA1, kB0, kB1);   // chunk t:   P in pb0, K(t+1)=kA
        region(t + 1, pb1, pb0, kB0, kB1, kA0, kA1);   // chunk t+1: P in pb1, K(t+2)=kB
    }
    // (final region's ephase/loadK/loadV are tail-clamped and harmless; all 32 chunks PV'd)

    // ---- epilogue: merge j-half (m,l), then out = gamma * acc / l + x ----
    const float gm = gamma[0];
#pragma unroll
    for (int it = 0; it < 4; ++it) {
        const int idx = ib + it * 16 + 4 * g;
        const float4 m0 = *reinterpret_cast<const float4*>(mArr + (size_t)b * NPOS + idx);
        const float4 m1 = *reinterpret_cast<const float4*>(mArr + ((size_t)NBATCH + b) * NPOS + idx);
        const float4 l0 = *reinterpret_cast<const float4*>(lArr + (size_t)b * NPOS + idx);
        const float4 l1 = *reinterpret_cast<const float4*>(lArr + ((size_t)NBATCH + b) * NPOS + idx);
        float inv[4];
        {
            const float mx = fmaxf(m0.x, m1.x);
            inv[0] = 1.0f / (l0.x * exp2f((m0.x - mx) * L2E) + l1.x * exp2f((m1.x - mx) * L2E));
            const float my = fmaxf(m0.y, m1.y);
            inv[1] = 1.0f / (l0.y * exp2f((m0.y - my) * L2E) + l1.y * exp2f((m1.y - my) * L2E));
            const float mz = fmaxf(m0.z, m1.z);
            inv[2] = 1.0f / (l0.z * exp2f((m0.z - mz) * L2E) + l1.z * exp2f((m1.z - mz) * L2E));
            const float mw = fmaxf(m0.w, m1.w);
            inv[3] = 1.0f / (l0.w * exp2f((m0.w - mw) * L2E) + l1.w * exp2f((m1.w - mw) * L2E));
        }
#pragma unroll
        for (int ct = 0; ct < 4; ++ct) {
            const int c = cw + ct * 16 + lr;
            const size_t base = (size_t)(b * CDIM + c) * NPOS + idx;
            const float4 xv = *reinterpret_cast<const float4*>(x + base);
            float4 ov;
            ov.x = gm * (acc[it][ct][0] * inv[0]) + xv.x;
            ov.y = gm * (acc[it][ct][1] * inv[1]) + xv.y;
            ov.z = gm * (acc[it][ct][2] * inv[2]) + xv.z;
            ov.w = gm * (acc[it][ct][3] * inv[3]) + xv.w;
            *reinterpret_cast<float4*>(out + base) = ov;
        }
    }
}

extern "C" void kernel_launch(void* const* d_in, const int* in_sizes, int n_in,
                              void* d_out, int out_size, void* d_ws, size_t ws_size,
                              hipStream_t stream)
{
    (void)in_sizes; (void)n_in; (void)out_size; (void)ws_size;

    const float* x     = (const float*)d_in[0];
    const float* wq    = (const float*)d_in[1];
    const float* bq    = (const float*)d_in[2];
    const float* wk    = (const float*)d_in[3];
    const float* bk    = (const float*)d_in[4];
    const float* wv    = (const float*)d_in[5];
    const float* bv    = (const float*)d_in[6];
    const float* gamma = (const float*)d_in[7];
    float* out = (float*)d_out;

    char* ws = (char*)d_ws;
    const size_t qkBytes = (size_t)NBATCH * NPOS * CQK * sizeof(_Float16);     //  2 MiB each
    const size_t vBytes  = (size_t)NBATCH * CDIM * NPOS * sizeof(_Float16);    // 16 MiB
    const size_t mlBytes = (size_t)2 * NBATCH * NPOS * sizeof(float);          // 128 KiB each (2 j-halves)
    const size_t xtBytes = (size_t)NBATCH * NPOS * CDIM * sizeof(_Float16);    // 16 MiB

    _Float16* Qp = (_Float16*)(ws);
    _Float16* Kp = (_Float16*)(ws + qkBytes);
    _Float16* Vp = (_Float16*)(ws + 2 * qkBytes);
    float* mArr  = (float*)(ws + 2 * qkBytes + vBytes);
    float* lArr  = (float*)(ws + 2 * qkBytes + vBytes + mlBytes);
    _Float16* Xt = (_Float16*)(ws + 2 * qkBytes + vBytes + 2 * mlBytes);
    _Float16* Wh = (_Float16*)(ws + 2 * qkBytes + vBytes + 2 * mlBytes + xtBytes);
    float* biasc = (float*)(ws + 2 * qkBytes + vBytes + 2 * mlBytes + xtBytes
                              + (size_t)640 * CDIM * sizeof(_Float16));
    // total ws use ~= 37.0 MiB

    w_cvt_kernel<<<dim3(640 * CDIM / 4 / 256), 256, 0, stream>>>(wq, bq, wk, bk, wv, bv, Wh, biasc);
    x_cvt_kernel<<<dim3(NPOS / 64, CDIM / 64, NBATCH), 256, 0, stream>>>(x, Xt);
    proj_gemm_kernel<<<dim3(NPOS / 128, 5, NBATCH), 256, 0, stream>>>(Wh, biasc, Xt, Qp, Kp, Vp);
    attn_stats_kernel<<<dim3(NPOS / 64, NBATCH, 2), 512, 0, stream>>>(Qp, Kp, mArr, lArr);
    attn_out_kernel<<<dim3(NPOS / 64 * NBATCH), 512, 0, stream>>>(x, Qp, Kp, Vp, mArr, lArr, gamma, out);
}